// Round 9
// baseline (413.138 us; speedup 1.0000x reference)
//
#include <hip/hip_runtime.h>

#define S    4096
#define CH   256
#define NB   8

#define BM   64
#define BN   64
#define KSPLIT 8

#define SFF  256.0f     // F pre-scale (power of 2; argmax-invariant)
#define SLL  1024.0f    // L pre-scale

#define NEG_INF (-3.402823466e38f)

typedef _Float16 half8 __attribute__((ext_vector_type(8)));
typedef float    f32x4 __attribute__((ext_vector_type(4)));

// ---------------------------------------------------------------------------
// out[:, 0:512] = input  (runs AFTER argmax — that slab holds the f16 panels)
__global__ void copy_fl(const float* __restrict__ x, float* __restrict__ out) {
    int i = blockIdx.x * 256 + threadIdx.x;          // float4 index
    const int per_b = 512 * S / 4;
    int b = i / per_b;
    int r = i - b * per_b;
    const float4* src = (const float4*)x;
    float4* dst = (float4*)out;
    dst[(size_t)b * (768 * S / 4) + r] = src[(size_t)b * per_b + r];
}

// ---------------------------------------------------------------------------
__global__ void compact(const int* __restrict__ flag, int* __restrict__ cnts,
                        int* __restrict__ qlist, int* __restrict__ klist) {
    __shared__ int sq[256], sk[256];
    int t = threadIdx.x;
    int base = t * 16;
    int f[16];
    int nq = 0, nk = 0;
    #pragma unroll
    for (int i = 0; i < 16; ++i) {
        f[i] = flag[base + i];
        nq += (f[i] == 1);
        nk += (f[i] == 0);
    }
    sq[t] = nq; sk[t] = nk;
    __syncthreads();
    for (int off = 1; off < 256; off <<= 1) {
        int vq = sq[t], vk = sk[t];
        int aq = (t >= off) ? sq[t - off] : 0;
        int ak = (t >= off) ? sk[t - off] : 0;
        __syncthreads();
        sq[t] = vq + aq; sk[t] = vk + ak;
        __syncthreads();
    }
    int pq = sq[t] - nq;
    int pk = sk[t] - nk;
    #pragma unroll
    for (int i = 0; i < 16; ++i) {
        if (f[i] == 1)      qlist[pq++] = base + i;
        else                klist[pk++] = base + i;
    }
    if (t == 255) { cnts[0] = sq[255]; cnts[1] = sk[255]; }
}

// ---------------------------------------------------------------------------
__global__ void invnorm_k(const float* __restrict__ x, float* __restrict__ invn) {
    int k4 = blockIdx.x * 256 + threadIdx.x;
    int b  = blockIdx.y;
    const float4* base = (const float4*)(x + ((size_t)b * 512 + 256) * S) + k4;
    float4 acc = { 0.f, 0.f, 0.f, 0.f };
    #pragma unroll 8
    for (int c = 0; c < CH; ++c) {
        float4 v = base[(size_t)c * (S / 4)];
        acc.x += v.x * v.x; acc.y += v.y * v.y;
        acc.z += v.z * v.z; acc.w += v.w * v.w;
    }
    float4 r;
    r.x = 1.0f / fmaxf(sqrtf(acc.x), 1e-12f);
    r.y = 1.0f / fmaxf(sqrtf(acc.y), 1e-12f);
    r.z = 1.0f / fmaxf(sqrtf(acc.z), 1e-12f);
    r.w = 1.0f / fmaxf(sqrtf(acc.w), 1e-12f);
    ((float4*)(invn + ((size_t)b << 12)))[k4] = r;
}

// ---------------------------------------------------------------------------
// f16 hi/lo panels, row-major [row][c], in the out[:,0:512] slab per batch:
//   FH | FL | LH | LL, each S*CH f16 (2 MB).
__global__ void pack_f16(const float* __restrict__ x, const int* __restrict__ cnts,
                         const int* __restrict__ qlist, float* __restrict__ out) {
    const int b = blockIdx.y;
    const int A = cnts[0];
    const int bound = (A + 127) & ~127;
    const int r = blockIdx.x * 32 + (threadIdx.x >> 3);
    if (r >= bound) return;
    const int cseg = (threadIdx.x & 7) * 32;
    _Float16* pb = (_Float16*)(out + (size_t)b * 768 * S);
    _Float16* FH = pb;
    _Float16* FL = pb + (size_t)S * CH;
    const float* src = x + (size_t)b * 512 * S;
    const int qq = (r < A) ? qlist[r] : -1;
    #pragma unroll
    for (int g = 0; g < 4; ++g) {
        union { _Float16 u[8]; float4 v; } hb, lb;
        #pragma unroll
        for (int j = 0; j < 8; ++j) {
            float v = 0.f;
            if (qq >= 0) v = src[(size_t)(cseg + g * 8 + j) * S + qq] * SFF;
            _Float16 h = (_Float16)v;
            float res = v - (float)h;
            hb.u[j] = h;
            lb.u[j] = (_Float16)res;
        }
        *(float4*)&FH[(size_t)r * CH + cseg + g * 8] = hb.v;
        *(float4*)&FL[(size_t)r * CH + cseg + g * 8] = lb.v;
    }
}

__global__ void pack_l16(const float* __restrict__ x, const int* __restrict__ cnts,
                         const int* __restrict__ klist, const float* __restrict__ invn,
                         float* __restrict__ out) {
    const int b = blockIdx.y;
    const int A = cnts[1];
    const int bound = (A + BN - 1) & ~(BN - 1);
    const int r = blockIdx.x * 32 + (threadIdx.x >> 3);
    if (r >= bound) return;
    const int cseg = (threadIdx.x & 7) * 32;
    _Float16* pb = (_Float16*)(out + (size_t)b * 768 * S);
    _Float16* LH = pb + 2 * (size_t)S * CH;
    _Float16* LL = pb + 3 * (size_t)S * CH;
    const float* src = x + ((size_t)b * 512 + 256) * S;
    int kk = -1; float w = 0.f;
    if (r < A) { kk = klist[r]; w = invn[((size_t)b << 12) + kk] * SLL; }
    #pragma unroll
    for (int g = 0; g < 4; ++g) {
        union { _Float16 u[8]; float4 v; } hb, lb;
        #pragma unroll
        for (int j = 0; j < 8; ++j) {
            float v = 0.f;
            if (kk >= 0) v = src[(size_t)(cseg + g * 8 + j) * S + kk] * w;
            _Float16 h = (_Float16)v;
            float res = v - (float)h;
            hb.u[j] = h;
            lb.u[j] = (_Float16)res;
        }
        *(float4*)&LH[(size_t)r * CH + cseg + g * 8] = hb.v;
        *(float4*)&LL[(size_t)r * CH + cseg + g * 8] = lb.v;
    }
}

// ---------------------------------------------------------------------------
// MFMA argmax GEMM, barrier-free / LDS-free (flatmm style):
// 4 waves per block, each wave owns 16 q-rows with the A panel (16 x 256,
// hi+lo f16) held in 64 VGPRs; B fragments stream global->reg (L1-shared
// across the block's waves). sim = Fh.Lh + Fh.Ll + Fl.Lh, fp32 accum,
// per-acc product order identical to the verified R8 kernel.
#define MFMA(A, B, C) __builtin_amdgcn_mfma_f32_16x16x32_f16((A), (B), (C), 0, 0, 0)

__launch_bounds__(256)
__global__ void argmax_mfma(const float* __restrict__ outbuf,
                            const int*  __restrict__ cnts,
                            const int*  __restrict__ klist,
                            float* __restrict__ pmax,
                            int*   __restrict__ pidx) {
    const int Aq    = cnts[0];
    const int Ak    = cnts[1];
    const int b     = blockIdx.y;
    const int split = blockIdx.x & (KSPLIT - 1);
    const int q0    = (blockIdx.x >> 3) * BM;
    if (q0 >= Aq) return;

    const int tid  = threadIdx.x;
    const int lane = tid & 63;
    const int wid  = tid >> 6;      // wave owns q rows q0 + wid*16 .. +15
    const int l15  = lane & 15;
    const int l4   = lane >> 4;

    const _Float16* pb  = (const _Float16*)(outbuf + (size_t)b * 768 * S);
    const _Float16* FHg = pb;
    const _Float16* FLg = pb + (size_t)S * CH;
    const _Float16* LHg = pb + 2 * (size_t)S * CH;
    const _Float16* LLg = pb + 3 * (size_t)S * CH;

    const int nkt = (Ak + BN - 1) / BN;
    const int kt0 = (nkt * split) / KSPLIT;
    const int kt1 = (nkt * (split + 1)) / KSPLIT;

    float rm[4]; int ri[4];
    #pragma unroll
    for (int i = 0; i < 4; ++i) { rm[i] = NEG_INF; ri[i] = 0; }

    if (kt0 < kt1) {
        // ---- A panel into registers (one-time): row q0+wid*16+l15, c = cc*32+l4*8
        half8 ah[8], al[8];
        {
            const size_t ro = (size_t)(q0 + wid * 16 + l15) * CH + l4 * 8;
            #pragma unroll
            for (int cc = 0; cc < 8; ++cc) {
                ah[cc] = *(const half8*)(FHg + ro + cc * 32);
                al[cc] = *(const half8*)(FLg + ro + cc * 32);
            }
        }

        // ---- B row pointers: row kt*64 + nt*16 + l15, c = l4*8 (+cc*32 imm)
        const _Float16* bp[8];      // [0..3]=LH nt, [4..7]=LL nt
        {
            const size_t ro = (size_t)(kt0 * BN + l15) * CH + l4 * 8;
            #pragma unroll
            for (int nt = 0; nt < 4; ++nt) {
                bp[nt]     = LHg + ro + (size_t)nt * 16 * CH;
                bp[4 + nt] = LLg + ro + (size_t)nt * 16 * CH;
            }
        }

        f32x4 acc[4];
        #pragma unroll
        for (int nt = 0; nt < 4; ++nt) acc[nt] = (f32x4){0.f, 0.f, 0.f, 0.f};

        for (int kt = kt0; kt < kt1; ++kt) {
            #pragma unroll
            for (int cc = 0; cc < 8; ++cc) {
                half8 bh0 = *(const half8*)(bp[0] + cc * 32);
                half8 bh1 = *(const half8*)(bp[1] + cc * 32);
                half8 bh2 = *(const half8*)(bp[2] + cc * 32);
                half8 bh3 = *(const half8*)(bp[3] + cc * 32);
                half8 bl0 = *(const half8*)(bp[4] + cc * 32);
                half8 bl1 = *(const half8*)(bp[5] + cc * 32);
                half8 bl2 = *(const half8*)(bp[6] + cc * 32);
                half8 bl3 = *(const half8*)(bp[7] + cc * 32);
                // per-acc order: hh, hl, lh  (identical to verified R8)
                acc[0] = MFMA(ah[cc], bh0, acc[0]);
                acc[1] = MFMA(ah[cc], bh1, acc[1]);
                acc[2] = MFMA(ah[cc], bh2, acc[2]);
                acc[3] = MFMA(ah[cc], bh3, acc[3]);
                acc[0] = MFMA(ah[cc], bl0, acc[0]);
                acc[1] = MFMA(ah[cc], bl1, acc[1]);
                acc[2] = MFMA(ah[cc], bl2, acc[2]);
                acc[3] = MFMA(ah[cc], bl3, acc[3]);
                acc[0] = MFMA(al[cc], bh0, acc[0]);
                acc[1] = MFMA(al[cc], bh1, acc[1]);
                acc[2] = MFMA(al[cc], bh2, acc[2]);
                acc[3] = MFMA(al[cc], bh3, acc[3]);
            }

            // fold k-tile into running (max, idx); ascending-k order
            const int kb = kt * BN;
            #pragma unroll
            for (int nt = 0; nt < 4; ++nt) {
                int kp = kb + nt * 16 + l15;
                if (kp < Ak) {
                    int kk = klist[kp];
                    #pragma unroll
                    for (int r = 0; r < 4; ++r) {
                        float sv = acc[nt][r];
                        if (sv > rm[r]) { rm[r] = sv; ri[r] = kk; }
                        else if (sv == rm[r] && kk < ri[r]) ri[r] = kk;
                    }
                }
                acc[nt] = (f32x4){0.f, 0.f, 0.f, 0.f};
            }

            #pragma unroll
            for (int p = 0; p < 8; ++p) bp[p] += (size_t)BN * CH;
        }
    }

    // reduce across the 16 lanes sharing each q-row group (xor within l15)
    #pragma unroll
    for (int r = 0; r < 4; ++r) {
        float m = rm[r]; int id = ri[r];
        #pragma unroll
        for (int off = 8; off; off >>= 1) {
            float om = __shfl_xor(m, off, 64);
            int   oi = __shfl_xor(id, off, 64);
            if (om > m || (om == m && oi < id)) { m = om; id = oi; }
        }
        if (l15 == 0) {
            int qp = q0 + wid * 16 + l4 * 4 + r;
            if (qp < Aq) {
                size_t o = ((size_t)((b << 12) + qp)) * KSPLIT + split;
                pmax[o] = m;
                pidx[o] = id;
            }
        }
    }
}

// ---------------------------------------------------------------------------
__global__ void combine(const int* __restrict__ cnts, const int* __restrict__ qlist,
                        const float* __restrict__ pmax, const int* __restrict__ pidx,
                        int* __restrict__ idxb) {
    int qp = blockIdx.x * 256 + threadIdx.x;
    int b  = blockIdx.y;
    if (qp >= cnts[0]) return;
    size_t base = (size_t)((b << 12) + qp) * KSPLIT;
    float m = pmax[base]; int id = pidx[base];
    #pragma unroll
    for (int s = 1; s < KSPLIT; ++s) {
        float om = pmax[base + s]; int oi = pidx[base + s];
        if (om > m) { m = om; id = oi; }
    }
    idxb[((size_t)b << 12) + qlist[qp]] = id;
}

// ---------------------------------------------------------------------------
__global__ void scatter_k(const float* __restrict__ x, const int* __restrict__ flag,
                          const int* __restrict__ idxb, float* __restrict__ out) {
    int e = blockIdx.x * 256 + threadIdx.x;
    int q = e & (S - 1);
    int c = (e >> 12) & 255;
    int b = e >> 20;
    float v = 0.f;
    if (flag[q] == 1) {
        int id = idxb[((size_t)b << 12) + q];
        v = x[((size_t)b * 512 + 256 + c) * S + id];
    }
    out[((size_t)b * 768 + 512 + c) * S + q] = v;
}

// ---------------------------------------------------------------------------
extern "C" void kernel_launch(void* const* d_in, const int* in_sizes, int n_in,
                              void* d_out, int out_size, void* d_ws, size_t ws_size,
                              hipStream_t stream) {
    const float* x    = (const float*)d_in[0];
    const int*   flag = (const int*)d_in[2];
    float*       out  = (float*)d_out;

    char* ws = (char*)d_ws;
    int*   cnts  = (int*)(ws);                 // 2 ints
    int*   qlist = (int*)(ws + 1024);          // 16 KB
    int*   klist = (int*)(ws + 17408);         // 16 KB
    float* invn  = (float*)(ws + 33792);       // 128 KB
    int*   idxb  = (int*)(ws + 164864);        // 128 KB
    float* pmax  = (float*)(ws + 295936);      // 1 MB  (8*4096*8)
    int*   pidx  = (int*)(ws + 1344512);       // 1 MB

    hipLaunchKernelGGL(compact,     dim3(1),                        dim3(256), 0, stream, flag, cnts, qlist, klist);
    hipLaunchKernelGGL(invnorm_k,   dim3(S / 4 / 256, NB),          dim3(256), 0, stream, x, invn);
    hipLaunchKernelGGL(pack_f16,    dim3(S / 32, NB),               dim3(256), 0, stream, x, cnts, qlist, out);
    hipLaunchKernelGGL(pack_l16,    dim3(S / 32, NB),               dim3(256), 0, stream, x, cnts, klist, invn, out);
    hipLaunchKernelGGL(argmax_mfma, dim3((S / BM) * KSPLIT, NB),    dim3(256), 0, stream,
                       out, cnts, klist, pmax, pidx);
    hipLaunchKernelGGL(combine,     dim3(S / 256, NB),              dim3(256), 0, stream, cnts, qlist, pmax, pidx, idxb);
    hipLaunchKernelGGL(copy_fl,     dim3((NB * 512 * S / 4) / 256), dim3(256), 0, stream, x, out);
    hipLaunchKernelGGL(scatter_k,   dim3((NB * CH * S) / 256),      dim3(256), 0, stream, x, flag, idxb, out);
}

// Round 10
// 204.916 us; speedup vs baseline: 2.0161x; 2.0161x over previous
//
#include <hip/hip_runtime.h>

#define S    4096
#define CH   256
#define NB   8

#define BM   128
#define BN   64
#define KSPLIT 8

#define SFF  256.0f     // F pre-scale (power of 2; argmax-invariant)
#define SLL  1024.0f    // L pre-scale

#define NEG_INF (-3.402823466e38f)

typedef _Float16 half8 __attribute__((ext_vector_type(8)));
typedef float    f32x4 __attribute__((ext_vector_type(4)));

// ---------------------------------------------------------------------------
// out[:, 0:512] = input  (runs AFTER argmax — that slab holds the f16 panels)
__global__ void copy_fl(const float* __restrict__ x, float* __restrict__ out) {
    int i = blockIdx.x * 256 + threadIdx.x;          // float4 index
    const int per_b = 512 * S / 4;
    int b = i / per_b;
    int r = i - b * per_b;
    const float4* src = (const float4*)x;
    float4* dst = (float4*)out;
    dst[(size_t)b * (768 * S / 4) + r] = src[(size_t)b * per_b + r];
}

// ---------------------------------------------------------------------------
__global__ void compact(const int* __restrict__ flag, int* __restrict__ cnts,
                        int* __restrict__ qlist, int* __restrict__ klist) {
    __shared__ int sq[256], sk[256];
    int t = threadIdx.x;
    int base = t * 16;
    int f[16];
    int nq = 0, nk = 0;
    #pragma unroll
    for (int i = 0; i < 16; ++i) {
        f[i] = flag[base + i];
        nq += (f[i] == 1);
        nk += (f[i] == 0);
    }
    sq[t] = nq; sk[t] = nk;
    __syncthreads();
    for (int off = 1; off < 256; off <<= 1) {
        int vq = sq[t], vk = sk[t];
        int aq = (t >= off) ? sq[t - off] : 0;
        int ak = (t >= off) ? sk[t - off] : 0;
        __syncthreads();
        sq[t] = vq + aq; sk[t] = vk + ak;
        __syncthreads();
    }
    int pq = sq[t] - nq;
    int pk = sk[t] - nk;
    #pragma unroll
    for (int i = 0; i < 16; ++i) {
        if (f[i] == 1)      qlist[pq++] = base + i;
        else                klist[pk++] = base + i;
    }
    if (t == 255) { cnts[0] = sq[255]; cnts[1] = sk[255]; }
}

// ---------------------------------------------------------------------------
__global__ void invnorm_k(const float* __restrict__ x, float* __restrict__ invn) {
    int k4 = blockIdx.x * 256 + threadIdx.x;
    int b  = blockIdx.y;
    const float4* base = (const float4*)(x + ((size_t)b * 512 + 256) * S) + k4;
    float4 acc = { 0.f, 0.f, 0.f, 0.f };
    #pragma unroll 8
    for (int c = 0; c < CH; ++c) {
        float4 v = base[(size_t)c * (S / 4)];
        acc.x += v.x * v.x; acc.y += v.y * v.y;
        acc.z += v.z * v.z; acc.w += v.w * v.w;
    }
    float4 r;
    r.x = 1.0f / fmaxf(sqrtf(acc.x), 1e-12f);
    r.y = 1.0f / fmaxf(sqrtf(acc.y), 1e-12f);
    r.z = 1.0f / fmaxf(sqrtf(acc.z), 1e-12f);
    r.w = 1.0f / fmaxf(sqrtf(acc.w), 1e-12f);
    ((float4*)(invn + ((size_t)b << 12)))[k4] = r;
}

// ---------------------------------------------------------------------------
// f16 hi/lo panels, row-major [row][c], in the out[:,0:512] slab per batch:
//   FH | FL | LH | LL, each S*CH f16 (2 MB).
__global__ void pack_f16(const float* __restrict__ x, const int* __restrict__ cnts,
                         const int* __restrict__ qlist, float* __restrict__ out) {
    const int b = blockIdx.y;
    const int A = cnts[0];
    const int bound = (A + BM - 1) & ~(BM - 1);
    const int r = blockIdx.x * 32 + (threadIdx.x >> 3);
    if (r >= bound) return;
    const int cseg = (threadIdx.x & 7) * 32;
    _Float16* pb = (_Float16*)(out + (size_t)b * 768 * S);
    _Float16* FH = pb;
    _Float16* FL = pb + (size_t)S * CH;
    const float* src = x + (size_t)b * 512 * S;
    const int qq = (r < A) ? qlist[r] : -1;
    #pragma unroll
    for (int g = 0; g < 4; ++g) {
        union { _Float16 u[8]; float4 v; } hb, lb;
        #pragma unroll
        for (int j = 0; j < 8; ++j) {
            float v = 0.f;
            if (qq >= 0) v = src[(size_t)(cseg + g * 8 + j) * S + qq] * SFF;
            _Float16 h = (_Float16)v;
            float res = v - (float)h;
            hb.u[j] = h;
            lb.u[j] = (_Float16)res;
        }
        *(float4*)&FH[(size_t)r * CH + cseg + g * 8] = hb.v;
        *(float4*)&FL[(size_t)r * CH + cseg + g * 8] = lb.v;
    }
}

__global__ void pack_l16(const float* __restrict__ x, const int* __restrict__ cnts,
                         const int* __restrict__ klist, const float* __restrict__ invn,
                         float* __restrict__ out) {
    const int b = blockIdx.y;
    const int A = cnts[1];
    const int bound = (A + BN - 1) & ~(BN - 1);
    const int r = blockIdx.x * 32 + (threadIdx.x >> 3);
    if (r >= bound) return;
    const int cseg = (threadIdx.x & 7) * 32;
    _Float16* pb = (_Float16*)(out + (size_t)b * 768 * S);
    _Float16* LH = pb + 2 * (size_t)S * CH;
    _Float16* LL = pb + 3 * (size_t)S * CH;
    const float* src = x + ((size_t)b * 512 + 256) * S;
    int kk = -1; float w = 0.f;
    if (r < A) { kk = klist[r]; w = invn[((size_t)b << 12) + kk] * SLL; }
    #pragma unroll
    for (int g = 0; g < 4; ++g) {
        union { _Float16 u[8]; float4 v; } hb, lb;
        #pragma unroll
        for (int j = 0; j < 8; ++j) {
            float v = 0.f;
            if (kk >= 0) v = src[(size_t)(cseg + g * 8 + j) * S + kk] * w;
            _Float16 h = (_Float16)v;
            float res = v - (float)h;
            hb.u[j] = h;
            lb.u[j] = (_Float16)res;
        }
        *(float4*)&LH[(size_t)r * CH + cseg + g * 8] = hb.v;
        *(float4*)&LL[(size_t)r * CH + cseg + g * 8] = lb.v;
    }
}

// ---------------------------------------------------------------------------
// MFMA argmax GEMM: A panel in registers (one-time preload), B staged via
// global_load_lds into a 4-buffer LDS ring with COUNTED vmcnt (never 0 in the
// main loop) + raw s_barrier (one per chunk). Argmax folds on COMPACT k
// indices (ascending == original order, so tie-break is preserved); combine
// translates via klist once.
#define MFMA(A, B, C) __builtin_amdgcn_mfma_f32_16x16x32_f16((A), (B), (C), 0, 0, 0)

#define GLDS(SRC, OFF) __builtin_amdgcn_global_load_lds( \
    (const __attribute__((address_space(1))) void*)(SRC), \
    (__attribute__((address_space(3))) void*)(lds + (OFF)), 16, 0, 0)

#define STAGE(LIT) do { GLDS(s4, (LIT) + woff); GLDS(s5, (LIT) + 4096 + woff); } while (0)

#define ADVB() do { \
    if ((tn & 7) == 7) { s4 += 32320; s5 += 32320; } \
    else               { s4 += 64;    s5 += 64;    } \
    ++tn; \
} while (0)

#define FOLD() do { \
    _Pragma("unroll") \
    for (int nt = 0; nt < 4; ++nt) { \
        int kp = kpb + nt * 16; \
        if (kp < Ak) { \
            _Pragma("unroll") \
            for (int mt = 0; mt < 2; ++mt) { \
                _Pragma("unroll") \
                for (int r = 0; r < 4; ++r) { \
                    const int ix = mt * 4 + r; \
                    float sv = acc[mt][nt][r]; \
                    if (sv > rm[ix]) { rm[ix] = sv; ri[ix] = kp; } \
                } \
            } \
        } \
        acc[0][nt] = (f32x4){0.f, 0.f, 0.f, 0.f}; \
        acc[1][nt] = (f32x4){0.f, 0.f, 0.f, 0.f}; \
    } \
    kpb += 64; \
} while (0)

#define ITER(TL, BUFL, NXL) do { \
    asm volatile("s_waitcnt vmcnt(4)" ::: "memory"); \
    __builtin_amdgcn_s_barrier(); \
    STAGE(NXL); \
    if (t + (TL) + 4 < nchunk) ADVB(); \
    _Pragma("unroll") \
    for (int nt = 0; nt < 4; ++nt) { \
        half8 bh = *(const half8*)(lds + (BUFL) + boff_h[nt]); \
        half8 bl = *(const half8*)(lds + (BUFL) + boff_l[nt]); \
        const int cc = (t + (TL)) & 7; \
        acc[0][nt] = MFMA(ah0[cc], bh, acc[0][nt]); \
        acc[1][nt] = MFMA(ah1[cc], bh, acc[1][nt]); \
        acc[0][nt] = MFMA(ah0[cc], bl, acc[0][nt]); \
        acc[1][nt] = MFMA(ah1[cc], bl, acc[1][nt]); \
        acc[0][nt] = MFMA(al0[cc], bh, acc[0][nt]); \
        acc[1][nt] = MFMA(al1[cc], bh, acc[1][nt]); \
    } \
    if (((TL) & 7) == 7) FOLD(); \
} while (0)

__launch_bounds__(256)
__global__ void argmax_mfma(const float* __restrict__ outbuf,
                            const int*  __restrict__ cnts,
                            float* __restrict__ pmax,
                            int*   __restrict__ pidx) {
    __shared__ __align__(1024) char lds[4 * 8192];   // 32 KB B ring

    const int Aq    = cnts[0];
    const int Ak    = cnts[1];
    const int b     = blockIdx.y;
    const int split = blockIdx.x & (KSPLIT - 1);     // low bits -> same XCD shares B slice
    const int q0    = (blockIdx.x >> 3) * BM;
    if (q0 >= Aq) return;

    const int tid  = threadIdx.x;
    const int lane = tid & 63;
    const int wid  = tid >> 6;      // wave owns q rows q0 + wid*32 .. +31
    const int l15  = lane & 15;
    const int l4   = lane >> 4;
    const int woff = wid * 1024;

    const _Float16* pb  = (const _Float16*)(outbuf + (size_t)b * 768 * S);
    const _Float16* FHg = pb;
    const _Float16* FLg = pb + (size_t)S * CH;
    const _Float16* LHg = pb + 2 * (size_t)S * CH;
    const _Float16* LLg = pb + 3 * (size_t)S * CH;

    const int nkt = (Ak + BN - 1) / BN;
    const int kt0 = (nkt * split) / KSPLIT;
    const int kt1 = (nkt * (split + 1)) / KSPLIT;
    const int nchunk = (kt1 - kt0) * 8;

    float rm[8]; int ri[8];
    #pragma unroll
    for (int i = 0; i < 8; ++i) { rm[i] = NEG_INF; ri[i] = 0; }

    // B LDS read byte-offsets (constant across chunks; R8-verified layout)
    int boff_h[4], boff_l[4];
    #pragma unroll
    for (int nt = 0; nt < 4; ++nt) {
        int rowb = nt * 16 + l15;
        int swzb = (rowb & 7) << 4;
        boff_h[nt] = rowb * 128 + ((l4 * 16)        ^ swzb);
        boff_l[nt] = rowb * 128 + (((l4 * 16) + 64) ^ swzb);
    }

    if (nchunk > 0) {
        // ---- A panel into registers (one-time): rows wid*32+l15, wid*32+16+l15
        half8 ah0[8], al0[8], ah1[8], al1[8];
        {
            const size_t ro0 = (size_t)(q0 + wid * 32 + l15)      * CH + l4 * 8;
            const size_t ro1 = (size_t)(q0 + wid * 32 + 16 + l15) * CH + l4 * 8;
            #pragma unroll
            for (int cc = 0; cc < 8; ++cc) {
                ah0[cc] = *(const half8*)(FHg + ro0 + cc * 32);
                al0[cc] = *(const half8*)(FLg + ro0 + cc * 32);
                ah1[cc] = *(const half8*)(FHg + ro1 + cc * 32);
                al1[cc] = *(const half8*)(FLg + ro1 + cc * 32);
            }
        }

        // ---- pre-swizzled global B source pointers (2 glds slots)
        const char *s4, *s5;
        {
            #define LSRC(P) ({ int s_ = (P) * 256 + tid; int row_ = s_ >> 3; \
                int ls_ = (s_ & 7) ^ (row_ & 7); \
                (const char*)(((ls_ < 4) ? LHg : LLg) + (size_t)(kt0 * BN + row_) * CH + (ls_ & 3) * 8); })
            s4 = LSRC(0); s5 = LSRC(1);
            #undef LSRC
        }
        int tn = 0;

        f32x4 acc[2][4];
        #pragma unroll
        for (int mt = 0; mt < 2; ++mt)
            #pragma unroll
            for (int nt = 0; nt < 4; ++nt) acc[mt][nt] = (f32x4){0.f, 0.f, 0.f, 0.f};

        int kpb = kt0 * BN + l15;

        // prologue: stage chunks 0,1,2 into bufs 0,1,2 (nchunk >= 8)
        STAGE(0);     ADVB();
        STAGE(8192);  ADVB();
        STAGE(16384); ADVB();

        for (int t = 0; t < nchunk; t += 8) {
            ITER(0, 0,     24576);
            ITER(1, 8192,  0);
            ITER(2, 16384, 8192);
            ITER(3, 24576, 16384);
            ITER(4, 0,     24576);
            ITER(5, 8192,  0);
            ITER(6, 16384, 8192);
            ITER(7, 24576, 16384);
        }
    }

    // reduce across the 16 lanes sharing each q-row group
    #pragma unroll
    for (int mt = 0; mt < 2; ++mt) {
        #pragma unroll
        for (int r = 0; r < 4; ++r) {
            const int ix = mt * 4 + r;
            float m = rm[ix]; int id = ri[ix];
            #pragma unroll
            for (int off = 8; off; off >>= 1) {
                float om = __shfl_xor(m, off, 64);
                int   oi = __shfl_xor(id, off, 64);
                if (om > m || (om == m && oi < id)) { m = om; id = oi; }
            }
            if (l15 == 0) {
                int qp = q0 + wid * 32 + mt * 16 + l4 * 4 + r;
                if (qp < Aq) {
                    size_t o = ((size_t)((b << 12) + qp)) * KSPLIT + split;
                    pmax[o] = m;
                    pidx[o] = id;
                }
            }
        }
    }
}

// ---------------------------------------------------------------------------
// combine k-split partials (pidx holds COMPACT k index) -> idxb = klist[best]
__global__ void combine(const int* __restrict__ cnts, const int* __restrict__ qlist,
                        const int* __restrict__ klist,
                        const float* __restrict__ pmax, const int* __restrict__ pidx,
                        int* __restrict__ idxb) {
    int qp = blockIdx.x * 256 + threadIdx.x;
    int b  = blockIdx.y;
    if (qp >= cnts[0]) return;
    size_t base = (size_t)((b << 12) + qp) * KSPLIT;
    float m = pmax[base]; int id = pidx[base];
    #pragma unroll
    for (int s = 1; s < KSPLIT; ++s) {
        float om = pmax[base + s]; int oi = pidx[base + s];
        if (om > m) { m = om; id = oi; }   // lower split = smaller compact k
    }
    idxb[((size_t)b << 12) + qlist[qp]] = klist[id];
}

// ---------------------------------------------------------------------------
__global__ void scatter_k(const float* __restrict__ x, const int* __restrict__ flag,
                          const int* __restrict__ idxb, float* __restrict__ out) {
    int e = blockIdx.x * 256 + threadIdx.x;
    int q = e & (S - 1);
    int c = (e >> 12) & 255;
    int b = e >> 20;
    float v = 0.f;
    if (flag[q] == 1) {
        int id = idxb[((size_t)b << 12) + q];
        v = x[((size_t)b * 512 + 256 + c) * S + id];
    }
    out[((size_t)b * 768 + 512 + c) * S + q] = v;
}

// ---------------------------------------------------------------------------
extern "C" void kernel_launch(void* const* d_in, const int* in_sizes, int n_in,
                              void* d_out, int out_size, void* d_ws, size_t ws_size,
                              hipStream_t stream) {
    const float* x    = (const float*)d_in[0];
    const int*   flag = (const int*)d_in[2];
    float*       out  = (float*)d_out;

    char* ws = (char*)d_ws;
    int*   cnts  = (int*)(ws);                 // 2 ints
    int*   qlist = (int*)(ws + 1024);          // 16 KB
    int*   klist = (int*)(ws + 17408);         // 16 KB
    float* invn  = (float*)(ws + 33792);       // 128 KB
    int*   idxb  = (int*)(ws + 164864);        // 128 KB
    float* pmax  = (float*)(ws + 295936);      // 1 MB  (8*4096*8)
    int*   pidx  = (int*)(ws + 1344512);       // 1 MB

    hipLaunchKernelGGL(compact,     dim3(1),                        dim3(256), 0, stream, flag, cnts, qlist, klist);
    hipLaunchKernelGGL(invnorm_k,   dim3(S / 4 / 256, NB),          dim3(256), 0, stream, x, invn);
    hipLaunchKernelGGL(pack_f16,    dim3(S / 32, NB),               dim3(256), 0, stream, x, cnts, qlist, out);
    hipLaunchKernelGGL(pack_l16,    dim3(S / 32, NB),               dim3(256), 0, stream, x, cnts, klist, invn, out);
    hipLaunchKernelGGL(argmax_mfma, dim3((S / BM) * KSPLIT, NB),    dim3(256), 0, stream,
                       out, cnts, pmax, pidx);
    hipLaunchKernelGGL(combine,     dim3(S / 256, NB),              dim3(256), 0, stream, cnts, qlist, klist, pmax, pidx, idxb);
    hipLaunchKernelGGL(copy_fl,     dim3((NB * 512 * S / 4) / 256), dim3(256), 0, stream, x, out);
    hipLaunchKernelGGL(scatter_k,   dim3((NB * CH * S) / 256),      dim3(256), 0, stream, x, flag, idxb, out);
}

// Round 11
// 199.475 us; speedup vs baseline: 2.0711x; 1.0273x over previous
//
#include <hip/hip_runtime.h>

#define S    4096
#define CH   256
#define NB   8

#define BM   128
#define BN   64
#define KSPLIT 4

#define SFF  256.0f     // F pre-scale (power of 2; argmax-invariant)
#define SLL  1024.0f    // L pre-scale

#define NEG_INF (-3.402823466e38f)

typedef _Float16 half8 __attribute__((ext_vector_type(8)));
typedef float    f32x4 __attribute__((ext_vector_type(4)));

// ---------------------------------------------------------------------------
// out[:, 0:512] = input  (runs AFTER argmax — that slab holds the f16 panels)
__global__ void copy_fl(const float* __restrict__ x, float* __restrict__ out) {
    int i = blockIdx.x * 256 + threadIdx.x;          // float4 index
    const int per_b = 512 * S / 4;
    int b = i / per_b;
    int r = i - b * per_b;
    const float4* src = (const float4*)x;
    float4* dst = (float4*)out;
    dst[(size_t)b * (768 * S / 4) + r] = src[(size_t)b * per_b + r];
}

// ---------------------------------------------------------------------------
// order-preserving compaction + inverse maps qpos/kpos
__global__ void compact(const int* __restrict__ flag, int* __restrict__ cnts,
                        int* __restrict__ qlist, int* __restrict__ klist,
                        int* __restrict__ qpos,  int* __restrict__ kpos) {
    __shared__ int sq[256], sk[256];
    int t = threadIdx.x;
    int base = t * 16;
    int f[16];
    int nq = 0, nk = 0;
    #pragma unroll
    for (int i = 0; i < 16; ++i) {
        f[i] = flag[base + i];
        nq += (f[i] == 1);
        nk += (f[i] == 0);
    }
    sq[t] = nq; sk[t] = nk;
    __syncthreads();
    for (int off = 1; off < 256; off <<= 1) {
        int vq = sq[t], vk = sk[t];
        int aq = (t >= off) ? sq[t - off] : 0;
        int ak = (t >= off) ? sk[t - off] : 0;
        __syncthreads();
        sq[t] = vq + aq; sk[t] = vk + ak;
        __syncthreads();
    }
    int pq = sq[t] - nq;
    int pk = sk[t] - nk;
    #pragma unroll
    for (int i = 0; i < 16; ++i) {
        if (f[i] == 1) { qpos[base + i] = pq; qlist[pq++] = base + i; }
        else           { kpos[base + i] = pk; klist[pk++] = base + i; }
    }
    if (t == 255) { cnts[0] = sq[255]; cnts[1] = sk[255]; }
}

// ---------------------------------------------------------------------------
__global__ void invnorm_k(const float* __restrict__ x, float* __restrict__ invn) {
    int k4 = blockIdx.x * 256 + threadIdx.x;
    int b  = blockIdx.y;
    const float4* base = (const float4*)(x + ((size_t)b * 512 + 256) * S) + k4;
    float4 acc = { 0.f, 0.f, 0.f, 0.f };
    #pragma unroll 8
    for (int c = 0; c < CH; ++c) {
        float4 v = base[(size_t)c * (S / 4)];
        acc.x += v.x * v.x; acc.y += v.y * v.y;
        acc.z += v.z * v.z; acc.w += v.w * v.w;
    }
    float4 r;
    r.x = 1.0f / fmaxf(sqrtf(acc.x), 1e-12f);
    r.y = 1.0f / fmaxf(sqrtf(acc.y), 1e-12f);
    r.z = 1.0f / fmaxf(sqrtf(acc.z), 1e-12f);
    r.w = 1.0f / fmaxf(sqrtf(acc.w), 1e-12f);
    ((float4*)(invn + ((size_t)b << 12)))[k4] = r;
}

// ---------------------------------------------------------------------------
// Coalesced transpose-pack: read 256-wide column strips into LDS, write f16
// hi/lo row-major panels at inverse-map rows. Values bitwise-identical to the
// verified gather packs. Panels per batch in out[:,0:512]: FH | FL | LH | LL.
__global__ void pack_f16t(const float* __restrict__ x, const int* __restrict__ flag,
                          const int* __restrict__ qpos, float* __restrict__ out) {
    __shared__ float T[16][257];
    const int b   = blockIdx.z;
    const int t   = threadIdx.x;
    const int q   = blockIdx.x * 256 + t;
    const int c0b = blockIdx.y * 64;
    _Float16* FH = (_Float16*)(out + (size_t)b * 768 * S);
    _Float16* FL = FH + (size_t)S * CH;
    const float* src = x + (size_t)b * 512 * S + blockIdx.x * 256;
    const bool active = (flag[q] == 1);
    const int row = active ? qpos[q] : 0;
    for (int c0 = c0b; c0 < c0b + 64; c0 += 16) {
        #pragma unroll
        for (int i = 0; i < 16; ++i)
            T[i][t] = src[(size_t)(c0 + i) * S + t];
        __syncthreads();
        if (active) {
            #pragma unroll
            for (int g = 0; g < 2; ++g) {
                union { _Float16 u[8]; float4 v; } hb, lb;
                #pragma unroll
                for (int j = 0; j < 8; ++j) {
                    float v = T[g * 8 + j][t] * SFF;
                    _Float16 h = (_Float16)v;
                    hb.u[j] = h;
                    lb.u[j] = (_Float16)(v - (float)h);
                }
                *(float4*)&FH[(size_t)row * CH + c0 + g * 8] = hb.v;
                *(float4*)&FL[(size_t)row * CH + c0 + g * 8] = lb.v;
            }
        }
        __syncthreads();
    }
}

__global__ void pack_l16t(const float* __restrict__ x, const int* __restrict__ flag,
                          const int* __restrict__ kpos, const float* __restrict__ invn,
                          float* __restrict__ out) {
    __shared__ float T[16][257];
    const int b   = blockIdx.z;
    const int t   = threadIdx.x;
    const int k   = blockIdx.x * 256 + t;
    const int c0b = blockIdx.y * 64;
    _Float16* LH = (_Float16*)(out + (size_t)b * 768 * S) + 2 * (size_t)S * CH;
    _Float16* LL = LH + (size_t)S * CH;
    const float* src = x + ((size_t)b * 512 + 256) * S + blockIdx.x * 256;
    const bool active = (flag[k] == 0);
    const int row = active ? kpos[k] : 0;
    const float w = active ? invn[((size_t)b << 12) + k] * SLL : 0.f;
    for (int c0 = c0b; c0 < c0b + 64; c0 += 16) {
        #pragma unroll
        for (int i = 0; i < 16; ++i)
            T[i][t] = src[(size_t)(c0 + i) * S + t];
        __syncthreads();
        if (active) {
            #pragma unroll
            for (int g = 0; g < 2; ++g) {
                union { _Float16 u[8]; float4 v; } hb, lb;
                #pragma unroll
                for (int j = 0; j < 8; ++j) {
                    float v = T[g * 8 + j][t] * w;
                    _Float16 h = (_Float16)v;
                    hb.u[j] = h;
                    lb.u[j] = (_Float16)(v - (float)h);
                }
                *(float4*)&LH[(size_t)row * CH + c0 + g * 8] = hb.v;
                *(float4*)&LL[(size_t)row * CH + c0 + g * 8] = lb.v;
            }
        }
        __syncthreads();
    }
}

// zero the padding rows [Aq, ceil128) of FH/FL and [Ak, ceil64) of LH/LL
__global__ void zero_pad(const int* __restrict__ cnts, float* __restrict__ out) {
    const int b  = blockIdx.y;
    const int Aq = cnts[0], Ak = cnts[1];
    const int aqp = (Aq + BM - 1) & ~(BM - 1);
    const int akp = (Ak + BN - 1) & ~(BN - 1);
    _Float16* pb = (_Float16*)(out + (size_t)b * 768 * S);
    int i = blockIdx.x * 256 + threadIdx.x;
    half8 z = { 0, 0, 0, 0, 0, 0, 0, 0 };
    if (i < 8192) {                 // F panels: 2 x (128 rows x 32 half8)
        int panel = i >> 12, idx = i & 4095;
        int row = Aq + (idx >> 5);
        if (row < aqp)
            *(half8*)(pb + (size_t)panel * S * CH + (size_t)row * CH + (idx & 31) * 8) = z;
    } else {                        // L panels: 2 x (64 rows x 32 half8)
        int j = i - 8192, panel = j >> 11, jdx = j & 2047;
        int row = Ak + (jdx >> 5);
        if (row < akp)
            *(half8*)(pb + (size_t)(2 + panel) * S * CH + (size_t)row * CH + (jdx & 31) * 8) = z;
    }
}

// ---------------------------------------------------------------------------
// MFMA argmax GEMM: A panel in registers, B via global_load_lds 4-buffer ring,
// counted vmcnt + raw s_barrier, setprio around MFMA. KSPLIT=4.
#define MFMA(A, B, C) __builtin_amdgcn_mfma_f32_16x16x32_f16((A), (B), (C), 0, 0, 0)

#define GLDS(SRC, OFF) __builtin_amdgcn_global_load_lds( \
    (const __attribute__((address_space(1))) void*)(SRC), \
    (__attribute__((address_space(3))) void*)(lds + (OFF)), 16, 0, 0)

#define STAGE(LIT) do { GLDS(s4, (LIT) + woff); GLDS(s5, (LIT) + 4096 + woff); } while (0)

#define ADVB() do { \
    if ((tn & 7) == 7) { s4 += 32320; s5 += 32320; } \
    else               { s4 += 64;    s5 += 64;    } \
    ++tn; \
} while (0)

#define FOLD() do { \
    _Pragma("unroll") \
    for (int nt = 0; nt < 4; ++nt) { \
        int kp = kpb + nt * 16; \
        if (kp < Ak) { \
            _Pragma("unroll") \
            for (int mt = 0; mt < 2; ++mt) { \
                _Pragma("unroll") \
                for (int r = 0; r < 4; ++r) { \
                    const int ix = mt * 4 + r; \
                    float sv = acc[mt][nt][r]; \
                    if (sv > rm[ix]) { rm[ix] = sv; ri[ix] = kp; } \
                } \
            } \
        } \
        acc[0][nt] = (f32x4){0.f, 0.f, 0.f, 0.f}; \
        acc[1][nt] = (f32x4){0.f, 0.f, 0.f, 0.f}; \
    } \
    kpb += 64; \
} while (0)

#define ITER(TL, BUFL, NXL) do { \
    asm volatile("s_waitcnt vmcnt(4)" ::: "memory"); \
    __builtin_amdgcn_s_barrier(); \
    STAGE(NXL); \
    if (t + (TL) + 4 < nchunk) ADVB(); \
    __builtin_amdgcn_s_setprio(1); \
    _Pragma("unroll") \
    for (int nt = 0; nt < 4; ++nt) { \
        half8 bh = *(const half8*)(lds + (BUFL) + boff_h[nt]); \
        half8 bl = *(const half8*)(lds + (BUFL) + boff_l[nt]); \
        const int cc = (t + (TL)) & 7; \
        acc[0][nt] = MFMA(ah0[cc], bh, acc[0][nt]); \
        acc[1][nt] = MFMA(ah1[cc], bh, acc[1][nt]); \
        acc[0][nt] = MFMA(ah0[cc], bl, acc[0][nt]); \
        acc[1][nt] = MFMA(ah1[cc], bl, acc[1][nt]); \
        acc[0][nt] = MFMA(al0[cc], bh, acc[0][nt]); \
        acc[1][nt] = MFMA(al1[cc], bh, acc[1][nt]); \
    } \
    __builtin_amdgcn_s_setprio(0); \
    if (((TL) & 7) == 7) FOLD(); \
} while (0)

__launch_bounds__(256)
__global__ void argmax_mfma(const float* __restrict__ outbuf,
                            const int*  __restrict__ cnts,
                            float* __restrict__ pmax,
                            int*   __restrict__ pidx) {
    __shared__ __align__(1024) char lds[4 * 8192];   // 32 KB B ring

    const int Aq    = cnts[0];
    const int Ak    = cnts[1];
    const int b     = blockIdx.y;
    const int split = blockIdx.x & (KSPLIT - 1);
    const int q0    = (blockIdx.x / KSPLIT) * BM;
    if (q0 >= Aq) return;

    const int tid  = threadIdx.x;
    const int lane = tid & 63;
    const int wid  = tid >> 6;      // wave owns q rows q0 + wid*32 .. +31
    const int l15  = lane & 15;
    const int l4   = lane >> 4;
    const int woff = wid * 1024;

    const _Float16* pb  = (const _Float16*)(outbuf + (size_t)b * 768 * S);
    const _Float16* FHg = pb;
    const _Float16* FLg = pb + (size_t)S * CH;
    const _Float16* LHg = pb + 2 * (size_t)S * CH;
    const _Float16* LLg = pb + 3 * (size_t)S * CH;

    const int nkt = (Ak + BN - 1) / BN;
    const int kt0 = (nkt * split) / KSPLIT;
    const int kt1 = (nkt * (split + 1)) / KSPLIT;
    const int nchunk = (kt1 - kt0) * 8;

    float rm[8]; int ri[8];
    #pragma unroll
    for (int i = 0; i < 8; ++i) { rm[i] = NEG_INF; ri[i] = 0; }

    // B LDS read byte-offsets (constant across chunks; R8-verified layout)
    int boff_h[4], boff_l[4];
    #pragma unroll
    for (int nt = 0; nt < 4; ++nt) {
        int rowb = nt * 16 + l15;
        int swzb = (rowb & 7) << 4;
        boff_h[nt] = rowb * 128 + ((l4 * 16)        ^ swzb);
        boff_l[nt] = rowb * 128 + (((l4 * 16) + 64) ^ swzb);
    }

    if (nchunk > 0) {
        // ---- A panel into registers (one-time)
        half8 ah0[8], al0[8], ah1[8], al1[8];
        {
            const size_t ro0 = (size_t)(q0 + wid * 32 + l15)      * CH + l4 * 8;
            const size_t ro1 = (size_t)(q0 + wid * 32 + 16 + l15) * CH + l4 * 8;
            #pragma unroll
            for (int cc = 0; cc < 8; ++cc) {
                ah0[cc] = *(const half8*)(FHg + ro0 + cc * 32);
                al0[cc] = *(const half8*)(FLg + ro0 + cc * 32);
                ah1[cc] = *(const half8*)(FHg + ro1 + cc * 32);
                al1[cc] = *(const half8*)(FLg + ro1 + cc * 32);
            }
        }

        // ---- pre-swizzled global B source pointers (2 glds slots)
        const char *s4, *s5;
        {
            #define LSRC(P) ({ int s_ = (P) * 256 + tid; int row_ = s_ >> 3; \
                int ls_ = (s_ & 7) ^ (row_ & 7); \
                (const char*)(((ls_ < 4) ? LHg : LLg) + (size_t)(kt0 * BN + row_) * CH + (ls_ & 3) * 8); })
            s4 = LSRC(0); s5 = LSRC(1);
            #undef LSRC
        }
        int tn = 0;

        f32x4 acc[2][4];
        #pragma unroll
        for (int mt = 0; mt < 2; ++mt)
            #pragma unroll
            for (int nt = 0; nt < 4; ++nt) acc[mt][nt] = (f32x4){0.f, 0.f, 0.f, 0.f};

        int kpb = kt0 * BN + l15;

        STAGE(0);     ADVB();
        STAGE(8192);  ADVB();
        STAGE(16384); ADVB();

        for (int t = 0; t < nchunk; t += 8) {
            ITER(0, 0,     24576);
            ITER(1, 8192,  0);
            ITER(2, 16384, 8192);
            ITER(3, 24576, 16384);
            ITER(4, 0,     24576);
            ITER(5, 8192,  0);
            ITER(6, 16384, 8192);
            ITER(7, 24576, 16384);
        }
    }

    // reduce across the 16 lanes sharing each q-row group
    #pragma unroll
    for (int mt = 0; mt < 2; ++mt) {
        #pragma unroll
        for (int r = 0; r < 4; ++r) {
            const int ix = mt * 4 + r;
            float m = rm[ix]; int id = ri[ix];
            #pragma unroll
            for (int off = 8; off; off >>= 1) {
                float om = __shfl_xor(m, off, 64);
                int   oi = __shfl_xor(id, off, 64);
                if (om > m || (om == m && oi < id)) { m = om; id = oi; }
            }
            if (l15 == 0) {
                int qp = q0 + wid * 32 + mt * 16 + l4 * 4 + r;
                if (qp < Aq) {
                    size_t o = ((size_t)((b << 12) + qp)) * KSPLIT + split;
                    pmax[o] = m;
                    pidx[o] = id;
                }
            }
        }
    }
}

// ---------------------------------------------------------------------------
// combine k-split partials (pidx holds COMPACT k index) -> idxb = klist[best]
__global__ void combine(const int* __restrict__ cnts, const int* __restrict__ qlist,
                        const int* __restrict__ klist,
                        const float* __restrict__ pmax, const int* __restrict__ pidx,
                        int* __restrict__ idxb) {
    int qp = blockIdx.x * 256 + threadIdx.x;
    int b  = blockIdx.y;
    if (qp >= cnts[0]) return;
    size_t base = (size_t)((b << 12) + qp) * KSPLIT;
    float m = pmax[base]; int id = pidx[base];
    #pragma unroll
    for (int s = 1; s < KSPLIT; ++s) {
        float om = pmax[base + s]; int oi = pidx[base + s];
        if (om > m) { m = om; id = oi; }   // lower split = smaller compact k
    }
    idxb[((size_t)b << 12) + qlist[qp]] = klist[id];
}

// ---------------------------------------------------------------------------
__global__ void scatter_k(const float* __restrict__ x, const int* __restrict__ flag,
                          const int* __restrict__ idxb, float* __restrict__ out) {
    int e = blockIdx.x * 256 + threadIdx.x;
    int q = e & (S - 1);
    int c = (e >> 12) & 255;
    int b = e >> 20;
    float v = 0.f;
    if (flag[q] == 1) {
        int id = idxb[((size_t)b << 12) + q];
        v = x[((size_t)b * 512 + 256 + c) * S + id];
    }
    out[((size_t)b * 768 + 512 + c) * S + q] = v;
}

// ---------------------------------------------------------------------------
extern "C" void kernel_launch(void* const* d_in, const int* in_sizes, int n_in,
                              void* d_out, int out_size, void* d_ws, size_t ws_size,
                              hipStream_t stream) {
    const float* x    = (const float*)d_in[0];
    const int*   flag = (const int*)d_in[2];
    float*       out  = (float*)d_out;

    char* ws = (char*)d_ws;
    int*   cnts  = (int*)(ws);                 // 2 ints
    int*   qlist = (int*)(ws + 1024);          // 16 KB
    int*   klist = (int*)(ws + 17408);         // 16 KB
    int*   qpos  = (int*)(ws + 33792);         // 16 KB
    int*   kpos  = (int*)(ws + 50176);         // 16 KB
    float* invn  = (float*)(ws + 66560);       // 128 KB
    int*   idxb  = (int*)(ws + 197632);        // 128 KB
    float* pmax  = (float*)(ws + 328704);      // 512 KB (8*4096*4)
    int*   pidx  = (int*)(ws + 852992);        // 512 KB

    hipLaunchKernelGGL(compact,     dim3(1),                        dim3(256), 0, stream, flag, cnts, qlist, klist, qpos, kpos);
    hipLaunchKernelGGL(invnorm_k,   dim3(S / 4 / 256, NB),          dim3(256), 0, stream, x, invn);
    hipLaunchKernelGGL(pack_f16t,   dim3(S / 256, 4, NB),           dim3(256), 0, stream, x, flag, qpos, out);
    hipLaunchKernelGGL(pack_l16t,   dim3(S / 256, 4, NB),           dim3(256), 0, stream, x, flag, kpos, invn, out);
    hipLaunchKernelGGL(zero_pad,    dim3(48, NB),                   dim3(256), 0, stream, cnts, out);
    hipLaunchKernelGGL(argmax_mfma, dim3((S / BM) * KSPLIT, NB),    dim3(256), 0, stream,
                       out, cnts, pmax, pidx);
    hipLaunchKernelGGL(combine,     dim3(S / 256, NB),              dim3(256), 0, stream, cnts, qlist, klist, pmax, pidx, idxb);
    hipLaunchKernelGGL(copy_fl,     dim3((NB * 512 * S / 4) / 256), dim3(256), 0, stream, x, out);
    hipLaunchKernelGGL(scatter_k,   dim3((NB * CH * S) / 256),      dim3(256), 0, stream, x, flag, idxb, out);
}

// Round 12
// 176.413 us; speedup vs baseline: 2.3419x; 1.1307x over previous
//
#include <hip/hip_runtime.h>

#define S    4096
#define CH   256
#define NB   8

#define BM   128
#define BN   64
#define KSPLIT 8

#define SFF  256.0f     // F pre-scale (power of 2; argmax-invariant)
#define SLL  1024.0f    // L pre-scale

#define NEG_INF (-3.402823466e38f)

typedef _Float16 half8 __attribute__((ext_vector_type(8)));
typedef float    f32x4 __attribute__((ext_vector_type(4)));

// ---------------------------------------------------------------------------
// order-preserving compaction + inverse maps qpos/kpos
__global__ void compact(const int* __restrict__ flag, int* __restrict__ cnts,
                        int* __restrict__ qlist, int* __restrict__ klist,
                        int* __restrict__ qpos,  int* __restrict__ kpos) {
    __shared__ int sq[256], sk[256];
    int t = threadIdx.x;
    int base = t * 16;
    int f[16];
    int nq = 0, nk = 0;
    #pragma unroll
    for (int i = 0; i < 16; ++i) {
        f[i] = flag[base + i];
        nq += (f[i] == 1);
        nk += (f[i] == 0);
    }
    sq[t] = nq; sk[t] = nk;
    __syncthreads();
    for (int off = 1; off < 256; off <<= 1) {
        int vq = sq[t], vk = sk[t];
        int aq = (t >= off) ? sq[t - off] : 0;
        int ak = (t >= off) ? sk[t - off] : 0;
        __syncthreads();
        sq[t] = vq + aq; sk[t] = vk + ak;
        __syncthreads();
    }
    int pq = sq[t] - nq;
    int pk = sk[t] - nk;
    #pragma unroll
    for (int i = 0; i < 16; ++i) {
        if (f[i] == 1) { qpos[base + i] = pq; qlist[pq++] = base + i; }
        else           { kpos[base + i] = pk; klist[pk++] = base + i; }
    }
    if (t == 255) { cnts[0] = sq[255]; cnts[1] = sk[255]; }
}

// ---------------------------------------------------------------------------
__global__ void invnorm_k(const float* __restrict__ x, float* __restrict__ invn) {
    int k4 = blockIdx.x * 256 + threadIdx.x;
    int b  = blockIdx.y;
    const float4* base = (const float4*)(x + ((size_t)b * 512 + 256) * S) + k4;
    float4 acc = { 0.f, 0.f, 0.f, 0.f };
    #pragma unroll 8
    for (int c = 0; c < CH; ++c) {
        float4 v = base[(size_t)c * (S / 4)];
        acc.x += v.x * v.x; acc.y += v.y * v.y;
        acc.z += v.z * v.z; acc.w += v.w * v.w;
    }
    float4 r;
    r.x = 1.0f / fmaxf(sqrtf(acc.x), 1e-12f);
    r.y = 1.0f / fmaxf(sqrtf(acc.y), 1e-12f);
    r.z = 1.0f / fmaxf(sqrtf(acc.z), 1e-12f);
    r.w = 1.0f / fmaxf(sqrtf(acc.w), 1e-12f);
    ((float4*)(invn + ((size_t)b << 12)))[k4] = r;
}

// ---------------------------------------------------------------------------
// Fused coalesced transpose-packs (F and L strips selected by blockIdx.y).
// Panels per batch in out[:,0:512]: FH | FL | LH | LL (row-major [row][c]).
__global__ void pack_both(const float* __restrict__ x, const int* __restrict__ flag,
                          const int* __restrict__ qpos, const int* __restrict__ kpos,
                          const float* __restrict__ invn, float* __restrict__ out) {
    __shared__ float T[16][257];
    const int b    = blockIdx.z;
    const int t    = threadIdx.x;
    const int s    = blockIdx.x * 256 + t;
    const bool isF = (blockIdx.y < 4);
    const int c0b  = (isF ? blockIdx.y : (blockIdx.y - 4)) * 64;

    _Float16* H;
    const float* src;
    bool active;
    int row;
    float w;
    if (isF) {
        H      = (_Float16*)(out + (size_t)b * 768 * S);
        src    = x + (size_t)b * 512 * S + blockIdx.x * 256;
        active = (flag[s] == 1);
        row    = active ? qpos[s] : 0;
        w      = SFF;
    } else {
        H      = (_Float16*)(out + (size_t)b * 768 * S) + 2 * (size_t)S * CH;
        src    = x + ((size_t)b * 512 + 256) * S + blockIdx.x * 256;
        active = (flag[s] == 0);
        row    = active ? kpos[s] : 0;
        w      = active ? invn[((size_t)b << 12) + s] * SLL : 0.f;
    }
    _Float16* L = H + (size_t)S * CH;

    for (int c0 = c0b; c0 < c0b + 64; c0 += 16) {
        #pragma unroll
        for (int i = 0; i < 16; ++i)
            T[i][t] = src[(size_t)(c0 + i) * S + t];
        __syncthreads();
        if (active) {
            #pragma unroll
            for (int g = 0; g < 2; ++g) {
                union { _Float16 u[8]; float4 v; } hb, lb;
                #pragma unroll
                for (int j = 0; j < 8; ++j) {
                    float v = T[g * 8 + j][t] * w;
                    _Float16 h = (_Float16)v;
                    hb.u[j] = h;
                    lb.u[j] = (_Float16)(v - (float)h);
                }
                *(float4*)&H[(size_t)row * CH + c0 + g * 8] = hb.v;
                *(float4*)&L[(size_t)row * CH + c0 + g * 8] = lb.v;
            }
        }
        __syncthreads();
    }
}

// zero the padding rows [Aq, ceil128) of FH/FL and [Ak, ceil64) of LH/LL
__global__ void zero_pad(const int* __restrict__ cnts, float* __restrict__ out) {
    const int b  = blockIdx.y;
    const int Aq = cnts[0], Ak = cnts[1];
    const int aqp = (Aq + BM - 1) & ~(BM - 1);
    const int akp = (Ak + BN - 1) & ~(BN - 1);
    _Float16* pb = (_Float16*)(out + (size_t)b * 768 * S);
    int i = blockIdx.x * 256 + threadIdx.x;
    half8 z = { 0, 0, 0, 0, 0, 0, 0, 0 };
    if (i < 8192) {                 // F panels: 2 x (128 rows x 32 half8)
        int panel = i >> 12, idx = i & 4095;
        int row = Aq + (idx >> 5);
        if (row < aqp)
            *(half8*)(pb + (size_t)panel * S * CH + (size_t)row * CH + (idx & 31) * 8) = z;
    } else {                        // L panels: 2 x (64 rows x 32 half8)
        int j = i - 8192, panel = j >> 11, jdx = j & 2047;
        int row = Ak + (jdx >> 5);
        if (row < akp)
            *(half8*)(pb + (size_t)(2 + panel) * S * CH + (size_t)row * CH + (jdx & 31) * 8) = z;
    }
}

// ---------------------------------------------------------------------------
// MFMA argmax GEMM: A panel in registers; B via global_load_lds into a
// 6-buffer ring (3 pair-slots); TWO chunks per barrier phase; counted vmcnt(4);
// setprio around the MFMA cluster. KSPLIT=8.
#define MFMA(A, B, C) __builtin_amdgcn_mfma_f32_16x16x32_f16((A), (B), (C), 0, 0, 0)

#define GLDS(SRC, OFF) __builtin_amdgcn_global_load_lds( \
    (const __attribute__((address_space(1))) void*)(SRC), \
    (__attribute__((address_space(3))) void*)(lds + (OFF)), 16, 0, 0)

#define STAGE(OFF) do { GLDS(s4, (OFF) + woff); GLDS(s5, (OFF) + 4096 + woff); } while (0)

#define ADV() do { \
    if (tn + 1 < nchunk) { \
        if ((tn & 7) == 7) { s4 += 32320; s5 += 32320; } \
        else               { s4 += 64;    s5 += 64;    } \
    } \
    ++tn; \
} while (0)

#define FOLD() do { \
    _Pragma("unroll") \
    for (int nt = 0; nt < 4; ++nt) { \
        int kp = kpb + nt * 16; \
        if (kp < Ak) { \
            _Pragma("unroll") \
            for (int mt = 0; mt < 2; ++mt) { \
                _Pragma("unroll") \
                for (int r = 0; r < 4; ++r) { \
                    const int ix = mt * 4 + r; \
                    float sv = acc[mt][nt][r]; \
                    if (sv > rm[ix]) { rm[ix] = sv; ri[ix] = kp; } \
                } \
            } \
        } \
        acc[0][nt] = (f32x4){0.f, 0.f, 0.f, 0.f}; \
        acc[1][nt] = (f32x4){0.f, 0.f, 0.f, 0.f}; \
    } \
    kpb += 64; \
} while (0)

// one 32-c chunk: load all 8 B fragments, then the MFMA cluster.
// per-acc product order hh, hl, lh and ascending c — bitwise-same sims as R8/R10.
#define CBODY(BASE, CC) do { \
    const char* _bb = lds + (BASE); \
    half8 bh0 = *(const half8*)(_bb + boff_h[0]); \
    half8 bl0 = *(const half8*)(_bb + boff_l[0]); \
    half8 bh1 = *(const half8*)(_bb + boff_h[1]); \
    half8 bl1 = *(const half8*)(_bb + boff_l[1]); \
    half8 bh2 = *(const half8*)(_bb + boff_h[2]); \
    half8 bl2 = *(const half8*)(_bb + boff_l[2]); \
    half8 bh3 = *(const half8*)(_bb + boff_h[3]); \
    half8 bl3 = *(const half8*)(_bb + boff_l[3]); \
    acc[0][0] = MFMA(ah0[CC], bh0, acc[0][0]); \
    acc[1][0] = MFMA(ah1[CC], bh0, acc[1][0]); \
    acc[0][0] = MFMA(ah0[CC], bl0, acc[0][0]); \
    acc[1][0] = MFMA(ah1[CC], bl0, acc[1][0]); \
    acc[0][0] = MFMA(al0[CC], bh0, acc[0][0]); \
    acc[1][0] = MFMA(al1[CC], bh0, acc[1][0]); \
    acc[0][1] = MFMA(ah0[CC], bh1, acc[0][1]); \
    acc[1][1] = MFMA(ah1[CC], bh1, acc[1][1]); \
    acc[0][1] = MFMA(ah0[CC], bl1, acc[0][1]); \
    acc[1][1] = MFMA(ah1[CC], bl1, acc[1][1]); \
    acc[0][1] = MFMA(al0[CC], bh1, acc[0][1]); \
    acc[1][1] = MFMA(al1[CC], bh1, acc[1][1]); \
    acc[0][2] = MFMA(ah0[CC], bh2, acc[0][2]); \
    acc[1][2] = MFMA(ah1[CC], bh2, acc[1][2]); \
    acc[0][2] = MFMA(ah0[CC], bl2, acc[0][2]); \
    acc[1][2] = MFMA(ah1[CC], bl2, acc[1][2]); \
    acc[0][2] = MFMA(al0[CC], bh2, acc[0][2]); \
    acc[1][2] = MFMA(al1[CC], bh2, acc[1][2]); \
    acc[0][3] = MFMA(ah0[CC], bh3, acc[0][3]); \
    acc[1][3] = MFMA(ah1[CC], bh3, acc[1][3]); \
    acc[0][3] = MFMA(ah0[CC], bl3, acc[0][3]); \
    acc[1][3] = MFMA(ah1[CC], bl3, acc[1][3]); \
    acc[0][3] = MFMA(al0[CC], bh3, acc[0][3]); \
    acc[1][3] = MFMA(al1[CC], bh3, acc[1][3]); \
} while (0)

// one phase = 2 chunks between a single barrier; stage pair p+2 into sto.
#define PHASE(J) do { \
    asm volatile("s_waitcnt vmcnt(4)" ::: "memory"); \
    __builtin_amdgcn_s_barrier(); \
    STAGE(sto); ADV(); \
    STAGE(sto + 8192); ADV(); \
    __builtin_amdgcn_s_setprio(1); \
    CBODY(rdo,        2 * (J)); \
    CBODY(rdo + 8192, 2 * (J) + 1); \
    __builtin_amdgcn_s_setprio(0); \
    rdo = (rdo == 32768) ? 0 : rdo + 16384; \
    sto = (sto == 32768) ? 0 : sto + 16384; \
} while (0)

__launch_bounds__(256)
__global__ void argmax_mfma(const float* __restrict__ outbuf,
                            const int*  __restrict__ cnts,
                            float* __restrict__ pmax,
                            int*   __restrict__ pidx) {
    __shared__ __align__(1024) char lds[6 * 8192];   // 48 KB, 3 pair-slots

    const int Aq    = cnts[0];
    const int Ak    = cnts[1];
    const int b     = blockIdx.y;
    const int split = blockIdx.x & (KSPLIT - 1);
    const int q0    = (blockIdx.x >> 3) * BM;
    if (q0 >= Aq) return;

    const int tid  = threadIdx.x;
    const int lane = tid & 63;
    const int wid  = tid >> 6;      // wave owns q rows q0 + wid*32 .. +31
    const int l15  = lane & 15;
    const int l4   = lane >> 4;
    const int woff = wid * 1024;

    const _Float16* pb  = (const _Float16*)(outbuf + (size_t)b * 768 * S);
    const _Float16* FHg = pb;
    const _Float16* FLg = pb + (size_t)S * CH;
    const _Float16* LHg = pb + 2 * (size_t)S * CH;
    const _Float16* LLg = pb + 3 * (size_t)S * CH;

    const int nkt = (Ak + BN - 1) / BN;
    const int kt0 = (nkt * split) / KSPLIT;
    const int kt1 = (nkt * (split + 1)) / KSPLIT;
    const int nchunk = (kt1 - kt0) * 8;

    float rm[8]; int ri[8];
    #pragma unroll
    for (int i = 0; i < 8; ++i) { rm[i] = NEG_INF; ri[i] = 0; }

    // B LDS read byte-offsets (constant across chunks; R8-verified layout)
    int boff_h[4], boff_l[4];
    #pragma unroll
    for (int nt = 0; nt < 4; ++nt) {
        int rowb = nt * 16 + l15;
        int swzb = (rowb & 7) << 4;
        boff_h[nt] = rowb * 128 + ((l4 * 16)        ^ swzb);
        boff_l[nt] = rowb * 128 + (((l4 * 16) + 64) ^ swzb);
    }

    if (nchunk > 0) {
        // ---- A panel into registers (one-time)
        half8 ah0[8], al0[8], ah1[8], al1[8];
        {
            const size_t ro0 = (size_t)(q0 + wid * 32 + l15)      * CH + l4 * 8;
            const size_t ro1 = (size_t)(q0 + wid * 32 + 16 + l15) * CH + l4 * 8;
            #pragma unroll
            for (int cc = 0; cc < 8; ++cc) {
                ah0[cc] = *(const half8*)(FHg + ro0 + cc * 32);
                al0[cc] = *(const half8*)(FLg + ro0 + cc * 32);
                ah1[cc] = *(const half8*)(FHg + ro1 + cc * 32);
                al1[cc] = *(const half8*)(FLg + ro1 + cc * 32);
            }
        }

        // ---- pre-swizzled global B source pointers (2 glds slots)
        const char *s4, *s5;
        {
            #define LSRC(P) ({ int s_ = (P) * 256 + tid; int row_ = s_ >> 3; \
                int ls_ = (s_ & 7) ^ (row_ & 7); \
                (const char*)(((ls_ < 4) ? LHg : LLg) + (size_t)(kt0 * BN + row_) * CH + (ls_ & 3) * 8); })
            s4 = LSRC(0); s5 = LSRC(1);
            #undef LSRC
        }
        int tn = 0;

        f32x4 acc[2][4];
        #pragma unroll
        for (int mt = 0; mt < 2; ++mt)
            #pragma unroll
            for (int nt = 0; nt < 4; ++nt) acc[mt][nt] = (f32x4){0.f, 0.f, 0.f, 0.f};

        int kpb = kt0 * BN + l15;

        // prologue: stage pairs 0 (slot0) and 1 (slot1) -> 8 glds outstanding
        STAGE(0);     ADV();
        STAGE(8192);  ADV();
        STAGE(16384); ADV();
        STAGE(24576); ADV();

        int rdo = 0;        // read slot byte offset
        int sto = 32768;    // stage slot byte offset (pair p+2)
        const int ngroup = kt1 - kt0;
        for (int g = 0; g < ngroup; ++g) {     // one group = one k-tile = 4 phases
            PHASE(0);
            PHASE(1);
            PHASE(2);
            PHASE(3);
            FOLD();
        }
    }

    // reduce across the 16 lanes sharing each q-row group
    #pragma unroll
    for (int mt = 0; mt < 2; ++mt) {
        #pragma unroll
        for (int r = 0; r < 4; ++r) {
            const int ix = mt * 4 + r;
            float m = rm[ix]; int id = ri[ix];
            #pragma unroll
            for (int off = 8; off; off >>= 1) {
                float om = __shfl_xor(m, off, 64);
                int   oi = __shfl_xor(id, off, 64);
                if (om > m || (om == m && oi < id)) { m = om; id = oi; }
            }
            if (l15 == 0) {
                int qp = q0 + wid * 32 + mt * 16 + l4 * 4 + r;
                if (qp < Aq) {
                    size_t o = ((size_t)((b << 12) + qp)) * KSPLIT + split;
                    pmax[o] = m;
                    pidx[o] = id;
                }
            }
        }
    }
}

// ---------------------------------------------------------------------------
// combine k-split partials (pidx holds COMPACT k index) -> idxb = klist[best]
__global__ void combine(const int* __restrict__ cnts, const int* __restrict__ qlist,
                        const int* __restrict__ klist,
                        const float* __restrict__ pmax, const int* __restrict__ pidx,
                        int* __restrict__ idxb) {
    int qp = blockIdx.x * 256 + threadIdx.x;
    int b  = blockIdx.y;
    if (qp >= cnts[0]) return;
    size_t base = (size_t)((b << 12) + qp) * KSPLIT;
    float m = pmax[base]; int id = pidx[base];
    #pragma unroll
    for (int s = 1; s < KSPLIT; ++s) {
        float om = pmax[base + s]; int oi = pidx[base + s];
        if (om > m) { m = om; id = oi; }   // lower split = smaller compact k
    }
    idxb[((size_t)b << 12) + qlist[qp]] = klist[id];
}

// ---------------------------------------------------------------------------
// fused writeback: out[:,0:512] = x (float4 copy); out[:,512:768] = shifted
__global__ void writeback(const float* __restrict__ x, const int* __restrict__ flag,
                          const int* __restrict__ idxb, float* __restrict__ out) {
    int i = blockIdx.x * 256 + threadIdx.x;   // float4 slot within [768][1024]
    int b = blockIdx.y;
    int c = i >> 10;
    float4* dst = (float4*)(out + (size_t)b * 768 * S) + i;
    if (c < 512) {
        *dst = ((const float4*)(x + (size_t)b * 512 * S))[i];
    } else {
        const float* src = x + ((size_t)b * 512 + 256 + (c - 512)) * S;
        const int* ib = idxb + ((size_t)b << 12);
        int q = (i & 1023) * 4;
        float4 v = { 0.f, 0.f, 0.f, 0.f };
        if (flag[q + 0] == 1) v.x = src[ib[q + 0]];
        if (flag[q + 1] == 1) v.y = src[ib[q + 1]];
        if (flag[q + 2] == 1) v.z = src[ib[q + 2]];
        if (flag[q + 3] == 1) v.w = src[ib[q + 3]];
        *dst = v;
    }
}

// ---------------------------------------------------------------------------
extern "C" void kernel_launch(void* const* d_in, const int* in_sizes, int n_in,
                              void* d_out, int out_size, void* d_ws, size_t ws_size,
                              hipStream_t stream) {
    const float* x    = (const float*)d_in[0];
    const int*   flag = (const int*)d_in[2];
    float*       out  = (float*)d_out;

    char* ws = (char*)d_ws;
    int*   cnts  = (int*)(ws);                 // 2 ints
    int*   qlist = (int*)(ws + 1024);          // 16 KB
    int*   klist = (int*)(ws + 17408);         // 16 KB
    int*   qpos  = (int*)(ws + 33792);         // 16 KB
    int*   kpos  = (int*)(ws + 50176);         // 16 KB
    float* invn  = (float*)(ws + 66560);       // 128 KB
    int*   idxb  = (int*)(ws + 197632);        // 128 KB
    float* pmax  = (float*)(ws + 328704);      // 1 MB (8*4096*8)
    int*   pidx  = (int*)(ws + 1377280);       // 1 MB

    hipLaunchKernelGGL(compact,     dim3(1),                     dim3(256), 0, stream, flag, cnts, qlist, klist, qpos, kpos);
    hipLaunchKernelGGL(invnorm_k,   dim3(S / 4 / 256, NB),       dim3(256), 0, stream, x, invn);
    hipLaunchKernelGGL(pack_both,   dim3(S / 256, 8, NB),        dim3(256), 0, stream, x, flag, qpos, kpos, invn, out);
    hipLaunchKernelGGL(zero_pad,    dim3(48, NB),                dim3(256), 0, stream, cnts, out);
    hipLaunchKernelGGL(argmax_mfma, dim3((S / BM) * KSPLIT, NB), dim3(256), 0, stream, out, cnts, pmax, pidx);
    hipLaunchKernelGGL(combine,     dim3(S / 256, NB),           dim3(256), 0, stream, cnts, qlist, klist, pmax, pidx, idxb);
    hipLaunchKernelGGL(writeback,   dim3(768 * 1024 / 256, NB),  dim3(256), 0, stream, x, flag, idxb, out);
}

// Round 13
// 163.100 us; speedup vs baseline: 2.5330x; 1.0816x over previous
//
#include <hip/hip_runtime.h>

#define S    4096
#define CH   256
#define NB   8

#define BM   128
#define BN   64
#define KSPLIT 8

#define SFF  256.0f     // F pre-scale (power of 2; argmax-invariant)
#define SLL  1024.0f    // L pre-scale

#define NEG_INF (-3.402823466e38f)

typedef _Float16 half8 __attribute__((ext_vector_type(8)));
typedef float    f32x4 __attribute__((ext_vector_type(4)));

// ---------------------------------------------------------------------------
// order-preserving compaction + inverse maps qpos/kpos
__global__ void compact(const int* __restrict__ flag, int* __restrict__ cnts,
                        int* __restrict__ qlist, int* __restrict__ klist,
                        int* __restrict__ qpos,  int* __restrict__ kpos) {
    __shared__ int sq[256], sk[256];
    int t = threadIdx.x;
    int base = t * 16;
    int f[16];
    int nq = 0, nk = 0;
    #pragma unroll
    for (int i = 0; i < 16; ++i) {
        f[i] = flag[base + i];
        nq += (f[i] == 1);
        nk += (f[i] == 0);
    }
    sq[t] = nq; sk[t] = nk;
    __syncthreads();
    for (int off = 1; off < 256; off <<= 1) {
        int vq = sq[t], vk = sk[t];
        int aq = (t >= off) ? sq[t - off] : 0;
        int ak = (t >= off) ? sk[t - off] : 0;
        __syncthreads();
        sq[t] = vq + aq; sk[t] = vk + ak;
        __syncthreads();
    }
    int pq = sq[t] - nq;
    int pk = sk[t] - nk;
    #pragma unroll
    for (int i = 0; i < 16; ++i) {
        if (f[i] == 1) { qpos[base + i] = pq; qlist[pq++] = base + i; }
        else           { kpos[base + i] = pk; klist[pk++] = base + i; }
    }
    if (t == 255) { cnts[0] = sq[255]; cnts[1] = sk[255]; }
}

// ---------------------------------------------------------------------------
// Fused transpose-pack.
//  y<4 : F strips (y*64 c) -> F2 fragment-ordered layout (coalesced preload).
//  y==4: L full-column two-pass: pass A = sumsq per k (ascending c, fp32 chain
//        identical to the old invnorm kernel), pass B = scale+split+write.
// Panels per batch in out[:,0:512]: F2(4MB fragment-order) | LH | LL (row-major).
__global__ void pack_both(const float* __restrict__ x, const int* __restrict__ flag,
                          const int* __restrict__ qpos, const int* __restrict__ kpos,
                          float* __restrict__ out) {
    __shared__ float T[16][257];
    const int b = blockIdx.z;
    const int t = threadIdx.x;
    const int s = blockIdx.x * 256 + t;

    if (blockIdx.y < 4) {
        const int c0b = blockIdx.y * 64;
        const float* src = x + (size_t)b * 512 * S + blockIdx.x * 256;
        const bool active = (flag[s] == 1);
        const int row = active ? qpos[s] : 0;
        half8* F2 = (half8*)(out + (size_t)b * 768 * S);
        const int g  = row >> 4;
        const int sr = row & 15;
        for (int c0 = c0b; c0 < c0b + 64; c0 += 16) {
            #pragma unroll
            for (int i = 0; i < 16; ++i)
                T[i][t] = src[(size_t)(c0 + i) * S + t];
            __syncthreads();
            if (active) {
                #pragma unroll
                for (int g8 = 0; g8 < 2; ++g8) {
                    const int c  = c0 + g8 * 8;
                    const int cc = c >> 5;
                    const int l4 = (c >> 3) & 3;
                    half8 hb, lb;
                    #pragma unroll
                    for (int j = 0; j < 8; ++j) {
                        float v = T[g8 * 8 + j][t] * SFF;
                        _Float16 h = (_Float16)v;
                        hb[j] = h;
                        lb[j] = (_Float16)(v - (float)h);
                    }
                    F2[(size_t)(((g * 2 + 0) * 8 + cc) * 64) + sr * 4 + l4] = hb;
                    F2[(size_t)(((g * 2 + 1) * 8 + cc) * 64) + sr * 4 + l4] = lb;
                }
            }
            __syncthreads();
        }
    } else {
        const float* src = x + ((size_t)b * 512 + 256) * S + blockIdx.x * 256;
        const bool active = (flag[s] == 0);
        const int row = active ? kpos[s] : 0;
        _Float16* LH = (_Float16*)(out + (size_t)b * 768 * S) + 2 * (size_t)S * CH;
        _Float16* LL = LH + (size_t)S * CH;

        // pass A: sumsq per column (ascending c — same fp32 chain as before)
        float acc = 0.f;
        for (int c0 = 0; c0 < CH; c0 += 16) {
            #pragma unroll
            for (int i = 0; i < 16; ++i)
                T[i][t] = src[(size_t)(c0 + i) * S + t];
            __syncthreads();
            #pragma unroll
            for (int i = 0; i < 16; ++i) {
                float v = T[i][t];
                acc += v * v;
            }
            __syncthreads();
        }
        const float w = active ? (1.0f / fmaxf(sqrtf(acc), 1e-12f)) * SLL : 0.f;

        // pass B: scale, split, write (re-read is L2-hot)
        for (int c0 = 0; c0 < CH; c0 += 16) {
            #pragma unroll
            for (int i = 0; i < 16; ++i)
                T[i][t] = src[(size_t)(c0 + i) * S + t];
            __syncthreads();
            if (active) {
                #pragma unroll
                for (int g8 = 0; g8 < 2; ++g8) {
                    union { _Float16 u[8]; float4 v; } hb, lb;
                    #pragma unroll
                    for (int j = 0; j < 8; ++j) {
                        float v = T[g8 * 8 + j][t] * w;
                        _Float16 h = (_Float16)v;
                        hb.u[j] = h;
                        lb.u[j] = (_Float16)(v - (float)h);
                    }
                    *(float4*)&LH[(size_t)row * CH + c0 + g8 * 8] = hb.v;
                    *(float4*)&LL[(size_t)row * CH + c0 + g8 * 8] = lb.v;
                }
            }
            __syncthreads();
        }
    }
}

// zero padding rows: F2 fragment-order for F, row-major for LH/LL
__global__ void zero_pad(const int* __restrict__ cnts, float* __restrict__ out) {
    const int b  = blockIdx.y;
    const int Aq = cnts[0], Ak = cnts[1];
    const int aqp = (Aq + BM - 1) & ~(BM - 1);
    const int akp = (Ak + BN - 1) & ~(BN - 1);
    _Float16* pb = (_Float16*)(out + (size_t)b * 768 * S);
    int i = blockIdx.x * 256 + threadIdx.x;
    half8 z = { 0, 0, 0, 0, 0, 0, 0, 0 };
    if (i < 8192) {                 // F2: 2 panels x (128 rows x 32 slots)
        int p = i >> 12, rem = i & 4095;
        int row = Aq + (rem >> 5);
        int sl  = rem & 31;
        if (row < aqp) {
            half8* F2 = (half8*)pb;
            F2[(size_t)((((row >> 4) * 2 + p) * 8 + (sl >> 2)) * 64) + (row & 15) * 4 + (sl & 3)] = z;
        }
    } else {                        // L panels: 2 x (64 rows x 32 half8)
        int j = i - 8192, panel = j >> 11, jdx = j & 2047;
        int row = Ak + (jdx >> 5);
        if (row < akp)
            *(half8*)(pb + (size_t)(2 + panel) * S * CH + (size_t)row * CH + (jdx & 31) * 8) = z;
    }
}

// ---------------------------------------------------------------------------
// MFMA argmax GEMM: A panel in registers (coalesced F2 preload); B via
// global_load_lds 6-buffer ring (3 pair-slots), 2 chunks per barrier phase,
// counted vmcnt(4), setprio around MFMA. KSPLIT=8.
#define MFMA(A, B, C) __builtin_amdgcn_mfma_f32_16x16x32_f16((A), (B), (C), 0, 0, 0)

#define GLDS(SRC, OFF) __builtin_amdgcn_global_load_lds( \
    (const __attribute__((address_space(1))) void*)(SRC), \
    (__attribute__((address_space(3))) void*)(lds + (OFF)), 16, 0, 0)

#define STAGE(OFF) do { GLDS(s4, (OFF) + woff); GLDS(s5, (OFF) + 4096 + woff); } while (0)

#define ADV() do { \
    if (tn + 1 < nchunk) { \
        if ((tn & 7) == 7) { s4 += 32320; s5 += 32320; } \
        else               { s4 += 64;    s5 += 64;    } \
    } \
    ++tn; \
} while (0)

#define FOLD() do { \
    _Pragma("unroll") \
    for (int nt = 0; nt < 4; ++nt) { \
        int kp = kpb + nt * 16; \
        if (kp < Ak) { \
            _Pragma("unroll") \
            for (int mt = 0; mt < 2; ++mt) { \
                _Pragma("unroll") \
                for (int r = 0; r < 4; ++r) { \
                    const int ix = mt * 4 + r; \
                    float sv = acc[mt][nt][r]; \
                    if (sv > rm[ix]) { rm[ix] = sv; ri[ix] = kp; } \
                } \
            } \
        } \
        acc[0][nt] = (f32x4){0.f, 0.f, 0.f, 0.f}; \
        acc[1][nt] = (f32x4){0.f, 0.f, 0.f, 0.f}; \
    } \
    kpb += 64; \
} while (0)

#define CBODY(BASE, CC) do { \
    const char* _bb = lds + (BASE); \
    half8 bh0 = *(const half8*)(_bb + boff_h[0]); \
    half8 bl0 = *(const half8*)(_bb + boff_l[0]); \
    half8 bh1 = *(const half8*)(_bb + boff_h[1]); \
    half8 bl1 = *(const half8*)(_bb + boff_l[1]); \
    half8 bh2 = *(const half8*)(_bb + boff_h[2]); \
    half8 bl2 = *(const half8*)(_bb + boff_l[2]); \
    half8 bh3 = *(const half8*)(_bb + boff_h[3]); \
    half8 bl3 = *(const half8*)(_bb + boff_l[3]); \
    acc[0][0] = MFMA(ah0[CC], bh0, acc[0][0]); \
    acc[1][0] = MFMA(ah1[CC], bh0, acc[1][0]); \
    acc[0][0] = MFMA(ah0[CC], bl0, acc[0][0]); \
    acc[1][0] = MFMA(ah1[CC], bl0, acc[1][0]); \
    acc[0][0] = MFMA(al0[CC], bh0, acc[0][0]); \
    acc[1][0] = MFMA(al1[CC], bh0, acc[1][0]); \
    acc[0][1] = MFMA(ah0[CC], bh1, acc[0][1]); \
    acc[1][1] = MFMA(ah1[CC], bh1, acc[1][1]); \
    acc[0][1] = MFMA(ah0[CC], bl1, acc[0][1]); \
    acc[1][1] = MFMA(ah1[CC], bl1, acc[1][1]); \
    acc[0][1] = MFMA(al0[CC], bh1, acc[0][1]); \
    acc[1][1] = MFMA(al1[CC], bh1, acc[1][1]); \
    acc[0][2] = MFMA(ah0[CC], bh2, acc[0][2]); \
    acc[1][2] = MFMA(ah1[CC], bh2, acc[1][2]); \
    acc[0][2] = MFMA(ah0[CC], bl2, acc[0][2]); \
    acc[1][2] = MFMA(ah1[CC], bl2, acc[1][2]); \
    acc[0][2] = MFMA(al0[CC], bh2, acc[0][2]); \
    acc[1][2] = MFMA(al1[CC], bh2, acc[1][2]); \
    acc[0][3] = MFMA(ah0[CC], bh3, acc[0][3]); \
    acc[1][3] = MFMA(ah1[CC], bh3, acc[1][3]); \
    acc[0][3] = MFMA(ah0[CC], bl3, acc[0][3]); \
    acc[1][3] = MFMA(ah1[CC], bl3, acc[1][3]); \
    acc[0][3] = MFMA(al0[CC], bh3, acc[0][3]); \
    acc[1][3] = MFMA(al1[CC], bh3, acc[1][3]); \
} while (0)

#define PHASE(J) do { \
    asm volatile("s_waitcnt vmcnt(4)" ::: "memory"); \
    __builtin_amdgcn_s_barrier(); \
    STAGE(sto); ADV(); \
    STAGE(sto + 8192); ADV(); \
    __builtin_amdgcn_s_setprio(1); \
    CBODY(rdo,        2 * (J)); \
    CBODY(rdo + 8192, 2 * (J) + 1); \
    __builtin_amdgcn_s_setprio(0); \
    rdo = (rdo == 32768) ? 0 : rdo + 16384; \
    sto = (sto == 32768) ? 0 : sto + 16384; \
} while (0)

__launch_bounds__(256)
__global__ void argmax_mfma(const float* __restrict__ outbuf,
                            const int*  __restrict__ cnts,
                            float* __restrict__ pmax,
                            int*   __restrict__ pidx) {
    __shared__ __align__(1024) char lds[6 * 8192];   // 48 KB, 3 pair-slots

    const int Aq    = cnts[0];
    const int Ak    = cnts[1];
    const int b     = blockIdx.y;
    const int split = blockIdx.x & (KSPLIT - 1);
    const int q0    = (blockIdx.x >> 3) * BM;
    if (q0 >= Aq) return;

    const int tid  = threadIdx.x;
    const int lane = tid & 63;
    const int wid  = tid >> 6;      // wave owns q rows q0 + wid*32 .. +31
    const int l15  = lane & 15;
    const int l4   = lane >> 4;
    const int woff = wid * 1024;

    const _Float16* pb  = (const _Float16*)(outbuf + (size_t)b * 768 * S);
    const _Float16* LHg = pb + 2 * (size_t)S * CH;
    const _Float16* LLg = pb + 3 * (size_t)S * CH;

    const int nkt = (Ak + BN - 1) / BN;
    const int kt0 = (nkt * split) / KSPLIT;
    const int kt1 = (nkt * (split + 1)) / KSPLIT;
    const int nchunk = (kt1 - kt0) * 8;

    float rm[8]; int ri[8];
    #pragma unroll
    for (int i = 0; i < 8; ++i) { rm[i] = NEG_INF; ri[i] = 0; }

    int boff_h[4], boff_l[4];
    #pragma unroll
    for (int nt = 0; nt < 4; ++nt) {
        int rowb = nt * 16 + l15;
        int swzb = (rowb & 7) << 4;
        boff_h[nt] = rowb * 128 + ((l4 * 16)        ^ swzb);
        boff_l[nt] = rowb * 128 + (((l4 * 16) + 64) ^ swzb);
    }

    if (nchunk > 0) {
        // ---- A panel into registers: coalesced F2 fragment loads
        half8 ah0[8], al0[8], ah1[8], al1[8];
        {
            const half8* F2 = (const half8*)pb;
            const int g0 = (q0 >> 4) + wid * 2;
            const int lo = l15 * 4 + l4;
            #pragma unroll
            for (int cc = 0; cc < 8; ++cc) {
                ah0[cc] = F2[(size_t)((((g0    ) * 2 + 0) * 8 + cc) * 64) + lo];
                al0[cc] = F2[(size_t)((((g0    ) * 2 + 1) * 8 + cc) * 64) + lo];
                ah1[cc] = F2[(size_t)((((g0 + 1) * 2 + 0) * 8 + cc) * 64) + lo];
                al1[cc] = F2[(size_t)((((g0 + 1) * 2 + 1) * 8 + cc) * 64) + lo];
            }
        }

        // ---- pre-swizzled global B source pointers (2 glds slots)
        const char *s4, *s5;
        {
            #define LSRC(P) ({ int s_ = (P) * 256 + tid; int row_ = s_ >> 3; \
                int ls_ = (s_ & 7) ^ (row_ & 7); \
                (const char*)(((ls_ < 4) ? LHg : LLg) + (size_t)(kt0 * BN + row_) * CH + (ls_ & 3) * 8); })
            s4 = LSRC(0); s5 = LSRC(1);
            #undef LSRC
        }
        int tn = 0;

        f32x4 acc[2][4];
        #pragma unroll
        for (int mt = 0; mt < 2; ++mt)
            #pragma unroll
            for (int nt = 0; nt < 4; ++nt) acc[mt][nt] = (f32x4){0.f, 0.f, 0.f, 0.f};

        int kpb = kt0 * BN + l15;

        STAGE(0);     ADV();
        STAGE(8192);  ADV();
        STAGE(16384); ADV();
        STAGE(24576); ADV();

        int rdo = 0;
        int sto = 32768;
        const int ngroup = kt1 - kt0;
        for (int g = 0; g < ngroup; ++g) {
            PHASE(0);
            PHASE(1);
            PHASE(2);
            PHASE(3);
            FOLD();
        }
    }

    #pragma unroll
    for (int mt = 0; mt < 2; ++mt) {
        #pragma unroll
        for (int r = 0; r < 4; ++r) {
            const int ix = mt * 4 + r;
            float m = rm[ix]; int id = ri[ix];
            #pragma unroll
            for (int off = 8; off; off >>= 1) {
                float om = __shfl_xor(m, off, 64);
                int   oi = __shfl_xor(id, off, 64);
                if (om > m || (om == m && oi < id)) { m = om; id = oi; }
            }
            if (l15 == 0) {
                int qp = q0 + wid * 32 + mt * 16 + l4 * 4 + r;
                if (qp < Aq) {
                    size_t o = ((size_t)((b << 12) + qp)) * KSPLIT + split;
                    pmax[o] = m;
                    pidx[o] = id;
                }
            }
        }
    }
}

// ---------------------------------------------------------------------------
// combine k-split partials (pidx holds COMPACT k index) -> idxb = klist[best]
__global__ void combine(const int* __restrict__ cnts, const int* __restrict__ qlist,
                        const int* __restrict__ klist,
                        const float* __restrict__ pmax, const int* __restrict__ pidx,
                        int* __restrict__ idxb) {
    int qp = blockIdx.x * 256 + threadIdx.x;
    int b  = blockIdx.y;
    if (qp >= cnts[0]) return;
    size_t base = (size_t)((b << 12) + qp) * KSPLIT;
    float m = pmax[base]; int id = pidx[base];
    #pragma unroll
    for (int s = 1; s < KSPLIT; ++s) {
        float om = pmax[base + s]; int oi = pidx[base + s];
        if (om > m) { m = om; id = oi; }   // lower split = smaller compact k
    }
    idxb[((size_t)b << 12) + qlist[qp]] = klist[id];
}

// ---------------------------------------------------------------------------
// fused writeback: out[:,0:512] = x (float4 copy); out[:,512:768] = shifted
__global__ void writeback(const float* __restrict__ x, const int* __restrict__ flag,
                          const int* __restrict__ idxb, float* __restrict__ out) {
    int i = blockIdx.x * 256 + threadIdx.x;   // float4 slot within [768][1024]
    int b = blockIdx.y;
    int c = i >> 10;
    float4* dst = (float4*)(out + (size_t)b * 768 * S) + i;
    if (c < 512) {
        *dst = ((const float4*)(x + (size_t)b * 512 * S))[i];
    } else {
        const float* src = x + ((size_t)b * 512 + 256 + (c - 512)) * S;
        const int* ib = idxb + ((size_t)b << 12);
        int q = (i & 1023) * 4;
        float4 v = { 0.f, 0.f, 0.f, 0.f };
        if (flag[q + 0] == 1) v.x = src[ib[q + 0]];
        if (flag[q + 1] == 1) v.y = src[ib[q + 1]];
        if (flag[q + 2] == 1) v.z = src[ib[q + 2]];
        if (flag[q + 3] == 1) v.w = src[ib[q + 3]];
        *dst = v;
    }
}

// ---------------------------------------------------------------------------
extern "C" void kernel_launch(void* const* d_in, const int* in_sizes, int n_in,
                              void* d_out, int out_size, void* d_ws, size_t ws_size,
                              hipStream_t stream) {
    const float* x    = (const float*)d_in[0];
    const int*   flag = (const int*)d_in[2];
    float*       out  = (float*)d_out;

    char* ws = (char*)d_ws;
    int*   cnts  = (int*)(ws);                 // 2 ints
    int*   qlist = (int*)(ws + 1024);          // 16 KB
    int*   klist = (int*)(ws + 17408);         // 16 KB
    int*   qpos  = (int*)(ws + 33792);         // 16 KB
    int*   kpos  = (int*)(ws + 50176);         // 16 KB
    int*   idxb  = (int*)(ws + 66560);         // 128 KB
    float* pmax  = (float*)(ws + 197632);      // 1 MB (8*4096*8)
    int*   pidx  = (int*)(ws + 1246208);       // 1 MB

    hipLaunchKernelGGL(compact,     dim3(1),                     dim3(256), 0, stream, flag, cnts, qlist, klist, qpos, kpos);
    hipLaunchKernelGGL(pack_both,   dim3(S / 256, 5, NB),        dim3(256), 0, stream, x, flag, qpos, kpos, out);
    hipLaunchKernelGGL(zero_pad,    dim3(48, NB),                dim3(256), 0, stream, cnts, out);
    hipLaunchKernelGGL(argmax_mfma, dim3((S / BM) * KSPLIT, NB), dim3(256), 0, stream, out, cnts, pmax, pidx);
    hipLaunchKernelGGL(combine,     dim3(S / 256, NB),           dim3(256), 0, stream, cnts, qlist, klist, pmax, pidx, idxb);
    hipLaunchKernelGGL(writeback,   dim3(768 * 1024 / 256, NB),  dim3(256), 0, stream, x, flag, idxb, out);
}

// Round 14
// 158.330 us; speedup vs baseline: 2.6093x; 1.0301x over previous
//
#include <hip/hip_runtime.h>

#define S    4096
#define CH   256
#define NB   8

#define BM   64
#define BN   64
#define KSPLIT 8

#define SFF  256.0f     // F pre-scale (power of 2; argmax-invariant)
#define SLL  1024.0f    // L pre-scale

#define NEG_INF (-3.402823466e38f)

typedef _Float16 half8 __attribute__((ext_vector_type(8)));
typedef float    f32x4 __attribute__((ext_vector_type(4)));

// ---------------------------------------------------------------------------
// order-preserving compaction + inverse maps qpos/kpos
__global__ void compact(const int* __restrict__ flag, int* __restrict__ cnts,
                        int* __restrict__ qlist, int* __restrict__ klist,
                        int* __restrict__ qpos,  int* __restrict__ kpos) {
    __shared__ int sq[256], sk[256];
    int t = threadIdx.x;
    int base = t * 16;
    int f[16];
    int nq = 0, nk = 0;
    #pragma unroll
    for (int i = 0; i < 16; ++i) {
        f[i] = flag[base + i];
        nq += (f[i] == 1);
        nk += (f[i] == 0);
    }
    sq[t] = nq; sk[t] = nk;
    __syncthreads();
    for (int off = 1; off < 256; off <<= 1) {
        int vq = sq[t], vk = sk[t];
        int aq = (t >= off) ? sq[t - off] : 0;
        int ak = (t >= off) ? sk[t - off] : 0;
        __syncthreads();
        sq[t] = vq + aq; sk[t] = vk + ak;
        __syncthreads();
    }
    int pq = sq[t] - nq;
    int pk = sk[t] - nk;
    #pragma unroll
    for (int i = 0; i < 16; ++i) {
        if (f[i] == 1) { qpos[base + i] = pq; qlist[pq++] = base + i; }
        else           { kpos[base + i] = pk; klist[pk++] = base + i; }
    }
    if (t == 255) { cnts[0] = sq[255]; cnts[1] = sk[255]; }
}

// ---------------------------------------------------------------------------
// Fused transpose-pack.
//  y<4 : F strips (y*64 c) -> F2 fragment-ordered layout (coalesced preload).
//  y==4: L full-column two-pass: pass A = sumsq per k (ascending c), pass B =
//        scale+split+write.
// Panels per batch in out[:,0:512]: F2(4MB fragment-order) | LH | LL (row-major).
__global__ void pack_both(const float* __restrict__ x, const int* __restrict__ flag,
                          const int* __restrict__ qpos, const int* __restrict__ kpos,
                          float* __restrict__ out) {
    __shared__ float T[16][257];
    const int b = blockIdx.z;
    const int t = threadIdx.x;
    const int s = blockIdx.x * 256 + t;

    if (blockIdx.y < 4) {
        const int c0b = blockIdx.y * 64;
        const float* src = x + (size_t)b * 512 * S + blockIdx.x * 256;
        const bool active = (flag[s] == 1);
        const int row = active ? qpos[s] : 0;
        half8* F2 = (half8*)(out + (size_t)b * 768 * S);
        const int g  = row >> 4;
        const int sr = row & 15;
        for (int c0 = c0b; c0 < c0b + 64; c0 += 16) {
            #pragma unroll
            for (int i = 0; i < 16; ++i)
                T[i][t] = src[(size_t)(c0 + i) * S + t];
            __syncthreads();
            if (active) {
                #pragma unroll
                for (int g8 = 0; g8 < 2; ++g8) {
                    const int c  = c0 + g8 * 8;
                    const int cc = c >> 5;
                    const int l4 = (c >> 3) & 3;
                    half8 hb, lb;
                    #pragma unroll
                    for (int j = 0; j < 8; ++j) {
                        float v = T[g8 * 8 + j][t] * SFF;
                        _Float16 h = (_Float16)v;
                        hb[j] = h;
                        lb[j] = (_Float16)(v - (float)h);
                    }
                    F2[(size_t)(((g * 2 + 0) * 8 + cc) * 64) + sr * 4 + l4] = hb;
                    F2[(size_t)(((g * 2 + 1) * 8 + cc) * 64) + sr * 4 + l4] = lb;
                }
            }
            __syncthreads();
        }
    } else {
        const float* src = x + ((size_t)b * 512 + 256) * S + blockIdx.x * 256;
        const bool active = (flag[s] == 0);
        const int row = active ? kpos[s] : 0;
        _Float16* LH = (_Float16*)(out + (size_t)b * 768 * S) + 2 * (size_t)S * CH;
        _Float16* LL = LH + (size_t)S * CH;

        float acc = 0.f;
        for (int c0 = 0; c0 < CH; c0 += 16) {
            #pragma unroll
            for (int i = 0; i < 16; ++i)
                T[i][t] = src[(size_t)(c0 + i) * S + t];
            __syncthreads();
            #pragma unroll
            for (int i = 0; i < 16; ++i) {
                float v = T[i][t];
                acc += v * v;
            }
            __syncthreads();
        }
        const float w = active ? (1.0f / fmaxf(sqrtf(acc), 1e-12f)) * SLL : 0.f;

        for (int c0 = 0; c0 < CH; c0 += 16) {
            #pragma unroll
            for (int i = 0; i < 16; ++i)
                T[i][t] = src[(size_t)(c0 + i) * S + t];
            __syncthreads();
            if (active) {
                #pragma unroll
                for (int g8 = 0; g8 < 2; ++g8) {
                    union { _Float16 u[8]; float4 v; } hb, lb;
                    #pragma unroll
                    for (int j = 0; j < 8; ++j) {
                        float v = T[g8 * 8 + j][t] * w;
                        _Float16 h = (_Float16)v;
                        hb.u[j] = h;
                        lb.u[j] = (_Float16)(v - (float)h);
                    }
                    *(float4*)&LH[(size_t)row * CH + c0 + g8 * 8] = hb.v;
                    *(float4*)&LL[(size_t)row * CH + c0 + g8 * 8] = lb.v;
                }
            }
            __syncthreads();
        }
    }
}

// zero padding rows: F2 fragment-order for F, row-major for LH/LL
__global__ void zero_pad(const int* __restrict__ cnts, float* __restrict__ out) {
    const int b  = blockIdx.y;
    const int Aq = cnts[0], Ak = cnts[1];
    const int aqp = (Aq + BM - 1) & ~(BM - 1);
    const int akp = (Ak + BN - 1) & ~(BN - 1);
    _Float16* pb = (_Float16*)(out + (size_t)b * 768 * S);
    int i = blockIdx.x * 256 + threadIdx.x;
    half8 z = { 0, 0, 0, 0, 0, 0, 0, 0 };
    if (i < 8192) {                 // F2: 2 panels x (<=128 pad rows x 32 slots)
        int p = i >> 12, rem = i & 4095;
        int row = Aq + (rem >> 5);
        int sl  = rem & 31;
        if (row < aqp) {
            half8* F2 = (half8*)pb;
            F2[(size_t)((((row >> 4) * 2 + p) * 8 + (sl >> 2)) * 64) + (row & 15) * 4 + (sl & 3)] = z;
        }
    } else {                        // L panels: 2 x (64 rows x 32 half8)
        int j = i - 8192, panel = j >> 11, jdx = j & 2047;
        int row = Ak + (jdx >> 5);
        if (row < akp)
            *(half8*)(pb + (size_t)(2 + panel) * S * CH + (size_t)row * CH + (jdx & 31) * 8) = z;
    }
}

// ---------------------------------------------------------------------------
// MFMA argmax GEMM: light waves (16 q-rows each, A panel 64 regs), B via
// global_load_lds 6-buffer ring, 2 chunks per barrier phase, counted vmcnt(4),
// setprio. KSPLIT=8. 3 waves/SIMD target.
#define MFMA(A, B, C) __builtin_amdgcn_mfma_f32_16x16x32_f16((A), (B), (C), 0, 0, 0)

#define GLDS(SRC, OFF) __builtin_amdgcn_global_load_lds( \
    (const __attribute__((address_space(1))) void*)(SRC), \
    (__attribute__((address_space(3))) void*)(lds + (OFF)), 16, 0, 0)

#define STAGE(OFF) do { GLDS(s4, (OFF) + woff); GLDS(s5, (OFF) + 4096 + woff); } while (0)

#define ADV() do { \
    if (tn + 1 < nchunk) { \
        if ((tn & 7) == 7) { s4 += 32320; s5 += 32320; } \
        else               { s4 += 64;    s5 += 64;    } \
    } \
    ++tn; \
} while (0)

#define FOLD() do { \
    _Pragma("unroll") \
    for (int nt = 0; nt < 4; ++nt) { \
        int kp = kpb + nt * 16; \
        if (kp < Ak) { \
            _Pragma("unroll") \
            for (int r = 0; r < 4; ++r) { \
                float sv = acc[nt][r]; \
                if (sv > rm[r]) { rm[r] = sv; ri[r] = kp; } \
            } \
        } \
        acc[nt] = (f32x4){0.f, 0.f, 0.f, 0.f}; \
    } \
    kpb += 64; \
} while (0)

// one 32-c chunk; per-acc product order hh, hl, lh (bitwise-same as R8..R13)
#define CBODY(BASE, CC) do { \
    const char* _bh = lds + (BASE) + boff0h; \
    const char* _bl = lds + (BASE) + boff0l; \
    half8 bh0 = *(const half8*)(_bh); \
    half8 bl0 = *(const half8*)(_bl); \
    half8 bh1 = *(const half8*)(_bh + 2048); \
    half8 bl1 = *(const half8*)(_bl + 2048); \
    half8 bh2 = *(const half8*)(_bh + 4096); \
    half8 bl2 = *(const half8*)(_bl + 4096); \
    half8 bh3 = *(const half8*)(_bh + 6144); \
    half8 bl3 = *(const half8*)(_bl + 6144); \
    acc[0] = MFMA(ah[CC], bh0, acc[0]); \
    acc[1] = MFMA(ah[CC], bh1, acc[1]); \
    acc[2] = MFMA(ah[CC], bh2, acc[2]); \
    acc[3] = MFMA(ah[CC], bh3, acc[3]); \
    acc[0] = MFMA(ah[CC], bl0, acc[0]); \
    acc[1] = MFMA(ah[CC], bl1, acc[1]); \
    acc[2] = MFMA(ah[CC], bl2, acc[2]); \
    acc[3] = MFMA(ah[CC], bl3, acc[3]); \
    acc[0] = MFMA(al[CC], bh0, acc[0]); \
    acc[1] = MFMA(al[CC], bh1, acc[1]); \
    acc[2] = MFMA(al[CC], bh2, acc[2]); \
    acc[3] = MFMA(al[CC], bh3, acc[3]); \
} while (0)

#define PHASE(J) do { \
    asm volatile("s_waitcnt vmcnt(4)" ::: "memory"); \
    __builtin_amdgcn_s_barrier(); \
    STAGE(sto); ADV(); \
    STAGE(sto + 8192); ADV(); \
    __builtin_amdgcn_s_setprio(1); \
    CBODY(rdo,        2 * (J)); \
    CBODY(rdo + 8192, 2 * (J) + 1); \
    __builtin_amdgcn_s_setprio(0); \
    rdo = (rdo == 32768) ? 0 : rdo + 16384; \
    sto = (sto == 32768) ? 0 : sto + 16384; \
} while (0)

__launch_bounds__(256)
__global__ void argmax_mfma(const float* __restrict__ outbuf,
                            const int*  __restrict__ cnts,
                            float* __restrict__ pmax,
                            int*   __restrict__ pidx) {
    __shared__ __align__(1024) char lds[6 * 8192];   // 48 KB, 3 pair-slots

    const int Aq    = cnts[0];
    const int Ak    = cnts[1];
    const int b     = blockIdx.y;
    const int split = blockIdx.x & (KSPLIT - 1);
    const int q0    = (blockIdx.x >> 3) * BM;
    if (q0 >= Aq) return;

    const int tid  = threadIdx.x;
    const int lane = tid & 63;
    const int wid  = tid >> 6;      // wave owns q rows q0 + wid*16 .. +15
    const int l15  = lane & 15;
    const int l4   = lane >> 4;
    const int woff = wid * 1024;

    const _Float16* pb  = (const _Float16*)(outbuf + (size_t)b * 768 * S);
    const _Float16* LHg = pb + 2 * (size_t)S * CH;
    const _Float16* LLg = pb + 3 * (size_t)S * CH;

    const int nkt = (Ak + BN - 1) / BN;
    const int kt0 = (nkt * split) / KSPLIT;
    const int kt1 = (nkt * (split + 1)) / KSPLIT;
    const int nchunk = (kt1 - kt0) * 8;

    float rm[4]; int ri[4];
    #pragma unroll
    for (int i = 0; i < 4; ++i) { rm[i] = NEG_INF; ri[i] = 0; }

    // compressed B LDS read offsets: boff0l == boff0h ^ 64 (exact: the swizzle
    // (l15&7)<<4 only touches bits 4-6 and l4*16 has no bit 6), nt adds 2048.
    const int boff0h = l15 * 128 + ((l4 * 16) ^ ((l15 & 7) << 4));
    const int boff0l = boff0h ^ 64;

    if (nchunk > 0) {
        // ---- A panel into registers: coalesced F2 fragment loads (16 x 1KB)
        half8 ah[8], al[8];
        {
            const half8* F2 = (const half8*)pb;
            const int g0 = (q0 >> 4) + wid;
            const int lo = l15 * 4 + l4;
            #pragma unroll
            for (int cc = 0; cc < 8; ++cc) {
                ah[cc] = F2[(size_t)(((g0 * 2 + 0) * 8 + cc) * 64) + lo];
                al[cc] = F2[(size_t)(((g0 * 2 + 1) * 8 + cc) * 64) + lo];
            }
        }

        // ---- pre-swizzled global B source pointers (2 glds slots)
        const char *s4, *s5;
        {
            #define LSRC(P) ({ int s_ = (P) * 256 + tid; int row_ = s_ >> 3; \
                int ls_ = (s_ & 7) ^ (row_ & 7); \
                (const char*)(((ls_ < 4) ? LHg : LLg) + (size_t)(kt0 * BN + row_) * CH + (ls_ & 3) * 8); })
            s4 = LSRC(0); s5 = LSRC(1);
            #undef LSRC
        }
        int tn = 0;

        f32x4 acc[4];
        #pragma unroll
        for (int nt = 0; nt < 4; ++nt) acc[nt] = (f32x4){0.f, 0.f, 0.f, 0.f};

        int kpb = kt0 * BN + l15;

        STAGE(0);     ADV();
        STAGE(8192);  ADV();
        STAGE(16384); ADV();
        STAGE(24576); ADV();

        int rdo = 0;
        int sto = 32768;
        const int ngroup = kt1 - kt0;
        for (int g = 0; g < ngroup; ++g) {
            PHASE(0);
            PHASE(1);
            PHASE(2);
            PHASE(3);
            FOLD();
        }
    }

    // reduce across the 16 lanes sharing each q-row group
    #pragma unroll
    for (int r = 0; r < 4; ++r) {
        float m = rm[r]; int id = ri[r];
        #pragma unroll
        for (int off = 8; off; off >>= 1) {
            float om = __shfl_xor(m, off, 64);
            int   oi = __shfl_xor(id, off, 64);
            if (om > m || (om == m && oi < id)) { m = om; id = oi; }
        }
        if (l15 == 0) {
            int qp = q0 + wid * 16 + l4 * 4 + r;
            if (qp < Aq) {
                size_t o = ((size_t)((b << 12) + qp)) * KSPLIT + split;
                pmax[o] = m;
                pidx[o] = id;
            }
        }
    }
}

// ---------------------------------------------------------------------------
// combine k-split partials (pidx holds COMPACT k index) -> idxb = klist[best]
__global__ void combine(const int* __restrict__ cnts, const int* __restrict__ qlist,
                        const int* __restrict__ klist,
                        const float* __restrict__ pmax, const int* __restrict__ pidx,
                        int* __restrict__ idxb) {
    int qp = blockIdx.x * 256 + threadIdx.x;
    int b  = blockIdx.y;
    if (qp >= cnts[0]) return;
    size_t base = (size_t)((b << 12) + qp) * KSPLIT;
    float m = pmax[base]; int id = pidx[base];
    #pragma unroll
    for (int s = 1; s < KSPLIT; ++s) {
        float om = pmax[base + s]; int oi = pidx[base + s];
        if (om > m) { m = om; id = oi; }   // lower split = smaller compact k
    }
    idxb[((size_t)b << 12) + qlist[qp]] = klist[id];
}

// ---------------------------------------------------------------------------
// fused writeback: out[:,0:512] = x (float4 copy); out[:,512:768] = shifted
__global__ void writeback(const float* __restrict__ x, const int* __restrict__ flag,
                          const int* __restrict__ idxb, float* __restrict__ out) {
    int i = blockIdx.x * 256 + threadIdx.x;   // float4 slot within [768][1024]
    int b = blockIdx.y;
    int c = i >> 10;
    float4* dst = (float4*)(out + (size_t)b * 768 * S) + i;
    if (c < 512) {
        *dst = ((const float4*)(x + (size_t)b * 512 * S))[i];
    } else {
        const float* src = x + ((size_t)b * 512 + 256 + (c - 512)) * S;
        const int* ib = idxb + ((size_t)b << 12);
        int q = (i & 1023) * 4;
        float4 v = { 0.f, 0.f, 0.f, 0.f };
        if (flag[q + 0] == 1) v.x = src[ib[q + 0]];
        if (flag[q + 1] == 1) v.y = src[ib[q + 1]];
        if (flag[q + 2] == 1) v.z = src[ib[q + 2]];
        if (flag[q + 3] == 1) v.w = src[ib[q + 3]];
        *dst = v;
    }
}

// ---------------------------------------------------------------------------
extern "C" void kernel_launch(void* const* d_in, const int* in_sizes, int n_in,
                              void* d_out, int out_size, void* d_ws, size_t ws_size,
                              hipStream_t stream) {
    const float* x    = (const float*)d_in[0];
    const int*   flag = (const int*)d_in[2];
    float*       out  = (float*)d_out;

    char* ws = (char*)d_ws;
    int*   cnts  = (int*)(ws);                 // 2 ints
    int*   qlist = (int*)(ws + 1024);          // 16 KB
    int*   klist = (int*)(ws + 17408);         // 16 KB
    int*   qpos  = (int*)(ws + 33792);         // 16 KB
    int*   kpos  = (int*)(ws + 50176);         // 16 KB
    int*   idxb  = (int*)(ws + 66560);         // 128 KB
    float* pmax  = (float*)(ws + 197632);      // 1 MB (8*4096*8)
    int*   pidx  = (int*)(ws + 1246208);       // 1 MB

    hipLaunchKernelGGL(compact,     dim3(1),                     dim3(256), 0, stream, flag, cnts, qlist, klist, qpos, kpos);
    hipLaunchKernelGGL(pack_both,   dim3(S / 256, 5, NB),        dim3(256), 0, stream, x, flag, qpos, kpos, out);
    hipLaunchKernelGGL(zero_pad,    dim3(48, NB),                dim3(256), 0, stream, cnts, out);
    hipLaunchKernelGGL(argmax_mfma, dim3((S / BM) * KSPLIT, NB), dim3(256), 0, stream, out, cnts, pmax, pidx);
    hipLaunchKernelGGL(combine,     dim3(S / 256, NB),           dim3(256), 0, stream, cnts, qlist, klist, pmax, pidx, idxb);
    hipLaunchKernelGGL(writeback,   dim3(768 * 1024 / 256, NB),  dim3(256), 0, stream, x, flag, idxb, out);
}